// Round 13
// baseline (131.098 us; speedup 1.0000x reference)
//
#include <hip/hip_runtime.h>
#include <hip/hip_bf16.h>
#include <math.h>

// ---------------------------------------------------------------------------
// GraphBased_selfAttnLayer — collapsed attention path, 5 launches.
//
//   G_v  = (S_{v-1} K)^T V            (MFMA, K-dim 8192, VT-layout + alignbit)
//   M_u  = scale * sum_v cw[u][v] G_v
//   attn = sum_u S_{u-1}(Q M_u) + cb*colsum(V); h = x + LN1(attn);
//   l2 = LN2(h) (LDS only); z = l2@m1w^T (fused) ; BN ; out = h + relu@m2w^T
//
// Launches: qkv -> g -> combine -> attn+LN+z (512 thr, 16-row, grid 512,
//           x-prefetch) -> out (512 thr, 16-row, grid 512, out-prefetch).
//
// ws (bytes):
//   QbG bf16 [8194][256]   @ 0
//   KT  bf16 [256][8192]   @  4,195,328
//   VT  bf16 [256][8200]   @  8,389,632   (guard cols 0/8193; VT[j][c]=V[c-1][j])
//   GP  f32 [48][256][256] @ 12,588,032   <- after combine: Z f32 [8192][128]
//   MT  bf16 [3][256][256] @ 25,170,944
//   SVP f32 [256][256]     @ 25,564,160
//   SVC f32 [256]          @ 25,826,304
//   RED f32 [512]          @ 25,827,328
//   ZSP f32 [512][256]     @ 25,829,376   (ends 26,353,664)
// ---------------------------------------------------------------------------

#define N_ 8192
#define D_ 256
#define H_ 128
#define EPSF 1e-5f

typedef unsigned short ushort_t;
typedef unsigned int uint_t;
typedef __attribute__((ext_vector_type(8))) short bf16x8;
typedef __attribute__((ext_vector_type(4))) short bf16x4;
typedef __attribute__((ext_vector_type(4))) float f32x4;

static const size_t OFF_QB  = 0;
static const size_t OFF_KT  = 4195328;
static const size_t OFF_VT  = 8389632;
static const size_t OFF_GP  = 12588032;
static const size_t OFF_MT  = 25170944;
static const size_t OFF_SVP = 25564160;
static const size_t OFF_SVC = 25826304;
static const size_t OFF_RED = 25827328;
static const size_t OFF_ZSP = 25829376;
static const size_t WS_NEED = 26353664;

#define VT_S 8200   // VT row stride (elems)

__device__ __forceinline__ ushort_t f2bf(float f) {
    __hip_bfloat16 h = __float2bfloat16(f);
    return reinterpret_cast<ushort_t&>(h);
}

__device__ __forceinline__ bf16x8 cvt8(float4 f0, float4 f1) {
    bf16x8 o;
    o[0] = (short)f2bf(f0.x); o[1] = (short)f2bf(f0.y);
    o[2] = (short)f2bf(f0.z); o[3] = (short)f2bf(f0.w);
    o[4] = (short)f2bf(f1.x); o[5] = (short)f2bf(f1.y);
    o[6] = (short)f2bf(f1.z); o[7] = (short)f2bf(f1.w);
    return o;
}

__device__ __forceinline__ float waveSum(float v)
{
#pragma unroll
    for (int o = 32; o > 0; o >>= 1) v += __shfl_xor(v, o);
    return v;
}

// ---------------------------------------------------------------------------
// qkv via MFMA with LDS-staged operands (proven, unchanged).
// ---------------------------------------------------------------------------
__global__ void __launch_bounds__(256)
qkv_mfma(const float* __restrict__ x,
         const float* __restrict__ wq, const float* __restrict__ bq,
         const float* __restrict__ wk, const float* __restrict__ bk,
         const float* __restrict__ wv, const float* __restrict__ bv,
         ushort_t* __restrict__ QbG, ushort_t* __restrict__ KT,
         ushort_t* __restrict__ VT,
         float* __restrict__ RED, float* __restrict__ SVP)
{
    __shared__ ushort_t XS[32][264];
    __shared__ ushort_t WS[256][40];
    __shared__ float lds4[4];
    const int tid = threadIdx.x, lane = tid & 63, wid = tid >> 6;
    const int sel = blockIdx.y;
    const int i0 = blockIdx.x * 32;
    const int jw = wid * 64;
    const int l15 = lane & 15, kg = lane >> 4;
    const float* W = (sel == 0) ? wq : ((sel == 1) ? wk : wv);
    const float* B = (sel == 0) ? bq : ((sel == 1) ? bk : bv);

    if (sel == 0 && blockIdx.x == 0) {
        QbG[tid] = 0; QbG[(size_t)8193 * 256 + tid] = 0;
        VT[(size_t)tid * VT_S] = 0; VT[(size_t)tid * VT_S + 8193] = 0;
    }

#pragma unroll
    for (int p = 0; p < 4; ++p) {
        int lin = p * 256 + tid;
        int row = lin >> 5;
        int c8  = (lin & 31) * 8;
        const float* xp = x + (size_t)(i0 + row) * 256 + c8;
        *(bf16x8*)(&XS[row][c8]) = cvt8(*(const float4*)xp, *(const float4*)(xp + 4));
    }

    f32x4 acc[2][4];
#pragma unroll
    for (int mi = 0; mi < 2; ++mi)
#pragma unroll
        for (int ni = 0; ni < 4; ++ni) acc[mi][ni] = 0.0f;

    for (int k0 = 0; k0 < 256; k0 += 32) {
        __syncthreads();
#pragma unroll
        for (int p = 0; p < 4; ++p) {
            int j  = p * 64 + (tid >> 2);
            int c8 = (tid & 3) * 8;
            const float* wp = W + (size_t)j * 256 + k0 + c8;
            *(bf16x8*)(&WS[j][c8]) = cvt8(*(const float4*)wp, *(const float4*)(wp + 4));
        }
        __syncthreads();

        bf16x8 a[2], b[4];
#pragma unroll
        for (int mi = 0; mi < 2; ++mi)
            a[mi] = *(const bf16x8*)(&XS[16 * mi + l15][k0 + 8 * kg]);
#pragma unroll
        for (int ni = 0; ni < 4; ++ni)
            b[ni] = *(const bf16x8*)(&WS[jw + 16 * ni + l15][8 * kg]);
#pragma unroll
        for (int mi = 0; mi < 2; ++mi)
#pragma unroll
            for (int ni = 0; ni < 4; ++ni)
                acc[mi][ni] = __builtin_amdgcn_mfma_f32_16x16x32_bf16(a[mi], b[ni], acc[mi][ni], 0, 0, 0);
    }

    float ssq = 0.0f;
    float colp[4] = {0.0f, 0.0f, 0.0f, 0.0f};

    if (sel == 0) {
#pragma unroll
        for (int mi = 0; mi < 2; ++mi)
#pragma unroll
            for (int ni = 0; ni < 4; ++ni) {
                const int col = jw + 16 * ni + l15;
                const float bias = B[col];
#pragma unroll
                for (int r = 0; r < 4; ++r) {
                    const int row = i0 + 16 * mi + 4 * kg + r;
                    float val = acc[mi][ni][r] + bias;
                    QbG[(size_t)(row + 1) * 256 + col] = f2bf(val);
                    ssq = fmaf(val, val, ssq);
                }
            }
    } else if (sel == 1) {
#pragma unroll
        for (int mi = 0; mi < 2; ++mi)
#pragma unroll
            for (int ni = 0; ni < 4; ++ni) {
                const int col = jw + 16 * ni + l15;   // d
                const float bias = B[col];
                const int tb = i0 + 16 * mi + 4 * kg;
                bf16x4 pk;
#pragma unroll
                for (int r = 0; r < 4; ++r) {
                    float val = acc[mi][ni][r] + bias;
                    ssq = fmaf(val, val, ssq);
                    pk[r] = (short)f2bf(val);
                }
                *(bf16x4*)(KT + (size_t)col * 8192 + tb) = pk;
            }
    } else {
#pragma unroll
        for (int mi = 0; mi < 2; ++mi)
#pragma unroll
            for (int ni = 0; ni < 4; ++ni) {
                const int col = jw + 16 * ni + l15;   // j
                const float bias = B[col];
                const int tb = i0 + 16 * mi + 4 * kg;
                float v0 = acc[mi][ni][0] + bias, v1 = acc[mi][ni][1] + bias;
                float v2 = acc[mi][ni][2] + bias, v3 = acc[mi][ni][3] + bias;
                colp[ni] += v0 + v1 + v2 + v3;
                ushort_t* p = VT + (size_t)col * VT_S + tb + 1;
                p[0] = f2bf(v0);
                *(uint_t*)(p + 1) = (uint_t)f2bf(v1) | ((uint_t)f2bf(v2) << 16);
                p[3] = f2bf(v3);
            }
    }

    if (sel < 2) {
        float s = ssq;
#pragma unroll
        for (int o = 32; o > 0; o >>= 1) s += __shfl_down(s, o);
        if (lane == 0) lds4[wid] = s;
        __syncthreads();
        if (tid == 0)
            RED[sel * 256 + blockIdx.x] = lds4[0] + lds4[1] + lds4[2] + lds4[3];
    } else {
#pragma unroll
        for (int ni = 0; ni < 4; ++ni) {
            float v = colp[ni];
            v += __shfl_xor(v, 16);
            v += __shfl_xor(v, 32);
            if (kg == 0)
                SVP[(size_t)blockIdx.x * 256 + jw + 16 * ni + l15] = v;
        }
    }
}

// ---------------------------------------------------------------------------
// G_v[d][j] = sum_t K[t][d] * V[t+1-v][j].  grid (4, 4, 16) = 256 blocks.
// Direct-load version (proven, unchanged).
// ---------------------------------------------------------------------------
__global__ void __launch_bounds__(256)
g_mfma(const ushort_t* __restrict__ KT, const ushort_t* __restrict__ VT,
       float* __restrict__ GP)
{
    const int tid = threadIdx.x, lane = tid & 63, wid = tid >> 6;
    const int d0 = blockIdx.x * 64;
    const int jw = blockIdx.y * 64 + wid * 16;
    const int ks = blockIdx.z;
    const int l15 = lane & 15, kg = lane >> 4;

    f32x4 acc[3][4];
#pragma unroll
    for (int v = 0; v < 3; ++v)
#pragma unroll
        for (int mi = 0; mi < 4; ++mi) acc[v][mi] = 0.0f;

    for (int tt = 0; tt < 512; tt += 32) {
        const int t0 = ks * 512 + tt;
        bf16x8 a[4];
#pragma unroll
        for (int mi = 0; mi < 4; ++mi)
            a[mi] = *(const bf16x8*)(KT + (size_t)(d0 + 16 * mi + l15) * 8192 + t0 + 8 * kg);

        const ushort_t* vp = VT + (size_t)(jw + l15) * VT_S + t0 + 8 * kg;
        uint4 r0 = *(const uint4*)vp;          // cols +0..7 -> v=2
        uint4 r2 = *(const uint4*)(vp + 2);    // cols +2..9 -> v=0
        uint4 m1;
        m1.x = (r0.x >> 16) | (r2.x << 16);
        m1.y = (r0.y >> 16) | (r2.y << 16);
        m1.z = (r0.z >> 16) | (r2.z << 16);
        m1.w = (r0.w >> 16) | (r2.w << 16);    // cols +1..8 -> v=1
        bf16x8 b2 = __builtin_bit_cast(bf16x8, r0);
        bf16x8 b0 = __builtin_bit_cast(bf16x8, r2);
        bf16x8 b1 = __builtin_bit_cast(bf16x8, m1);
#pragma unroll
        for (int mi = 0; mi < 4; ++mi) {
            acc[0][mi] = __builtin_amdgcn_mfma_f32_16x16x32_bf16(a[mi], b0, acc[0][mi], 0, 0, 0);
            acc[1][mi] = __builtin_amdgcn_mfma_f32_16x16x32_bf16(a[mi], b1, acc[1][mi], 0, 0, 0);
            acc[2][mi] = __builtin_amdgcn_mfma_f32_16x16x32_bf16(a[mi], b2, acc[2][mi], 0, 0, 0);
        }
    }

#pragma unroll
    for (int v = 0; v < 3; ++v) {
        float* gp = GP + (size_t)(ks * 3 + v) * 65536;
#pragma unroll
        for (int mi = 0; mi < 4; ++mi)
#pragma unroll
            for (int r = 0; r < 4; ++r)
                gp[(size_t)(d0 + 16 * mi + 4 * kg + r) * 256 + (jw + l15)]
                    = acc[v][mi][r];
    }
}

// ---------------------------------------------------------------------------
// MT[u][j][d] = scale * sum_v cw[u][v] * sum_ks GP[ks*3+v][d][j]  (bf16).
// (unchanged)
// ---------------------------------------------------------------------------
__global__ void combine_m(const float* __restrict__ GP, const float* __restrict__ cw,
                          const float* __restrict__ RED, const float* __restrict__ SVP,
                          const float* __restrict__ cb,
                          ushort_t* __restrict__ MT, float* __restrict__ SVC)
{
    __shared__ float lds8[8];
    __shared__ float scsh;
    const int d = blockIdx.x, j = threadIdx.x;

    float sq = RED[j], sk = RED[256 + j];
#pragma unroll
    for (int o = 32; o > 0; o >>= 1) { sq += __shfl_down(sq, o); sk += __shfl_down(sk, o); }
    if ((j & 63) == 0) { lds8[j >> 6] = sq; lds8[4 + (j >> 6)] = sk; }

    float g[3] = {0.0f, 0.0f, 0.0f};
    for (int ks = 0; ks < 16; ++ks)
#pragma unroll
        for (int v = 0; v < 3; ++v)
            g[v] += GP[(size_t)(ks * 3 + v) * 65536 + (size_t)d * 256 + j];

    __syncthreads();
    if (j == 0) {
        float SQ = lds8[0] + lds8[1] + lds8[2] + lds8[3];
        float SK = lds8[4] + lds8[5] + lds8[6] + lds8[7];
        scsh = rsqrtf(SQ) * rsqrtf(SK);
    }
    __syncthreads();
    const float sc = scsh;

#pragma unroll
    for (int u = 0; u < 3; ++u) {
        float m = sc * (cw[u * 3 + 0] * g[0] + cw[u * 3 + 1] * g[1] + cw[u * 3 + 2] * g[2]);
        MT[(size_t)u * 65536 + (size_t)j * 256 + d] = f2bf(m);
    }
    if (d == 0) {
        float s = 0.0f;
        for (int b = 0; b < 256; ++b) s += SVP[(size_t)b * 256 + j];
        SVC[j] = cb[0] * s;
    }
}

// ---------------------------------------------------------------------------
// attn + LN + z fused. 512 threads (8 waves), 16 rows/block, grid 512.
// x prefetched at entry (hides HBM latency under attention GEMM).
// Each wave: attn 16x32 cols; LN 2 rows; z 16 cols.
// ---------------------------------------------------------------------------
__global__ void __launch_bounds__(512)
attn_ln_z_mfma(const ushort_t* __restrict__ QbG, const ushort_t* __restrict__ MT,
               const float* __restrict__ SVC, const float* __restrict__ x,
               const float* __restrict__ ln1g, const float* __restrict__ ln1b,
               const float* __restrict__ ln2g, const float* __restrict__ ln2b,
               const float* __restrict__ m1w,
               float* __restrict__ h, float* __restrict__ Z,
               float* __restrict__ ZSP)
{
    __shared__ ushort_t QS[18][264];
    __shared__ float OUT[16][260];
    __shared__ ushort_t WS[128][40];
    const int tid = threadIdx.x, lane = tid & 63, wid = tid >> 6;  // wid 0..7
    const int i0 = blockIdx.x * 16;
    const int jw = wid * 32;
    const int l15 = lane & 15, kg = lane >> 4;

    // prefetch x for this wave's LN rows (consumed after attention GEMM)
    float4 xpre0 = *(const float4*)(x + (size_t)(i0 + wid * 2 + 0) * 256 + lane * 4);
    float4 xpre1 = *(const float4*)(x + (size_t)(i0 + wid * 2 + 1) * 256 + lane * 4);

    // stage Q tile: 18 rows x 32 units = 576 units over 512 threads
    {
        int row = tid >> 5, c8 = (tid & 31) * 8;
        *(bf16x8*)(&QS[row][c8]) = *(const bf16x8*)(QbG + (size_t)(i0 + row) * 256 + c8);
        int idx = tid + 512;
        if (idx < 576) {
            row = idx >> 5; c8 = (idx & 31) * 8;
            *(bf16x8*)(&QS[row][c8]) = *(const bf16x8*)(QbG + (size_t)(i0 + row) * 256 + c8);
        }
    }
    __syncthreads();

    // ---- 1) attention GEMM: A from LDS, B (MT) direct (L2-resident) ----
    f32x4 acc[2];
    acc[0] = 0.0f; acc[1] = 0.0f;

    for (int k0 = 0; k0 < 256; k0 += 32) {
        bf16x8 a[3], b[3][2];
#pragma unroll
        for (int u = 0; u < 3; ++u)
            a[u] = *(const bf16x8*)(&QS[l15 + u][k0 + 8 * kg]);
#pragma unroll
        for (int u = 0; u < 3; ++u)
#pragma unroll
            for (int ni = 0; ni < 2; ++ni)
                b[u][ni] = *(const bf16x8*)(MT + (size_t)u * 65536
                    + (size_t)(jw + 16 * ni + l15) * 256 + k0 + 8 * kg);
#pragma unroll
        for (int ni = 0; ni < 2; ++ni)
#pragma unroll
            for (int u = 0; u < 3; ++u)
                acc[ni] = __builtin_amdgcn_mfma_f32_16x16x32_bf16(
                    a[u], b[u][ni], acc[ni], 0, 0, 0);
    }

#pragma unroll
    for (int ni = 0; ni < 2; ++ni) {
        const int col = jw + 16 * ni + l15;
        const float sv = SVC[col];
#pragma unroll
        for (int r = 0; r < 4; ++r)
            OUT[4 * kg + r][col] = acc[ni][r] + sv;
    }
    __syncthreads();

    // ---- 2) LN (wave-per-row, 2 rows/wave): h -> global, l2 -> OUT ----
    const float4 g14 = *(const float4*)(ln1g + lane * 4);
    const float4 b14 = *(const float4*)(ln1b + lane * 4);
    const float4 g24 = *(const float4*)(ln2g + lane * 4);
    const float4 b24 = *(const float4*)(ln2b + lane * 4);
#pragma unroll
    for (int rr = 0; rr < 2; ++rr) {
        const int row_l = wid * 2 + rr;
        const size_t off = (size_t)(i0 + row_l) * 256 + lane * 4;

        float4 a4 = *(const float4*)&OUT[row_l][lane * 4];
        float m = waveSum(a4.x + a4.y + a4.z + a4.w) * (1.0f / D_);
        float4 d4 = make_float4(a4.x - m, a4.y - m, a4.z - m, a4.w - m);
        float var = waveSum(d4.x * d4.x + d4.y * d4.y + d4.z * d4.z + d4.w * d4.w) * (1.0f / D_);
        float rs = rsqrtf(var + EPSF);

        float4 x4 = (rr == 0) ? xpre0 : xpre1;
        float4 h4;
        h4.x = x4.x + d4.x * rs * g14.x + b14.x;
        h4.y = x4.y + d4.y * rs * g14.y + b14.y;
        h4.z = x4.z + d4.z * rs * g14.z + b14.z;
        h4.w = x4.w + d4.w * rs * g14.w + b14.w;
        *(float4*)(h + off) = h4;

        float m2 = waveSum(h4.x + h4.y + h4.z + h4.w) * (1.0f / D_);
        float4 e4 = make_float4(h4.x - m2, h4.y - m2, h4.z - m2, h4.w - m2);
        float v2 = waveSum(e4.x * e4.x + e4.y * e4.y + e4.z * e4.z + e4.w * e4.w) * (1.0f / D_);
        float rs2 = rsqrtf(v2 + EPSF);

        float4 o4;
        o4.x = e4.x * rs2 * g24.x + b24.x;
        o4.y = e4.y * rs2 * g24.y + b24.y;
        o4.z = e4.z * rs2 * g24.z + b24.z;
        o4.w = e4.w * rs2 * g24.w + b24.w;
        *(float4*)&OUT[row_l][lane * 4] = o4;   // l2 stays in LDS
    }
    __syncthreads();

    // ---- 3) z = l2 @ m1w^T from LDS; 8 waves each own 16 of 128 cols ----
    const int jz = wid * 16;
    f32x4 zacc;
    zacc = 0.0f;

    for (int k0 = 0; k0 < 256; k0 += 32) {
        if (k0) __syncthreads();
        // stage m1w chunk: 128 rows x 4 units = 512 units, one pass
        {
            int j  = tid >> 2;
            int c8 = (tid & 3) * 8;
            const float* wp = m1w + (size_t)j * 256 + k0 + c8;
            *(bf16x8*)(&WS[j][c8]) = cvt8(*(const float4*)wp, *(const float4*)(wp + 4));
        }
        __syncthreads();

        bf16x8 a, b;
        {
            const float* lp = &OUT[l15][k0 + 8 * kg];
            a = cvt8(*(const float4*)lp, *(const float4*)(lp + 4));
        }
        b = *(const bf16x8*)(&WS[jz + l15][8 * kg]);
        zacc = __builtin_amdgcn_mfma_f32_16x16x32_bf16(a, b, zacc, 0, 0, 0);
    }

    float s = 0.0f, q = 0.0f;
    const int col = jz + l15;
#pragma unroll
    for (int r = 0; r < 4; ++r) {
        float zv = zacc[r];
        Z[(size_t)(i0 + 4 * kg + r) * 128 + col] = zv;
        s += zv;
        q = fmaf(zv, zv, q);
    }
    s += __shfl_xor(s, 16); s += __shfl_xor(s, 32);
    q += __shfl_xor(q, 16); q += __shfl_xor(q, 32);
    if (kg == 0) {
        ZSP[(size_t)blockIdx.x * 256 + col] = s;
        ZSP[(size_t)blockIdx.x * 256 + 128 + col] = q;
    }
}

// ---------------------------------------------------------------------------
// out = h + relu(z*a+b) @ m2w^T. 512 threads (8 waves), 16 rows, grid 512.
// out RMW addend prefetched at entry; BN from ZSP (4-way split prologue);
// Z tile staged with affine+relu; m2w direct (L2-resident).
// ---------------------------------------------------------------------------
__global__ void __launch_bounds__(512)
gemm_out_mfma(const float* __restrict__ Z, const float* __restrict__ W,
              const float* __restrict__ ZSP,
              const float* __restrict__ bng, const float* __restrict__ bnb,
              float* __restrict__ out)
{
    __shared__ float bnA[128], bnB[128];
    __shared__ float pS[4][128], pQ[4][128];
    __shared__ ushort_t XS[16][136];
    const int tid = threadIdx.x, lane = tid & 63, wid = tid >> 6;  // 0..7
    const int i0 = blockIdx.x * 16;
    const int jw = wid * 32;
    const int l15 = lane & 15, kg = lane >> 4;

    // prefetch out RMW addend (h values) — consumed in epilogue
    float oprev[2][4];
#pragma unroll
    for (int ni = 0; ni < 2; ++ni)
#pragma unroll
        for (int r = 0; r < 4; ++r)
            oprev[ni][r] = out[(size_t)(i0 + 4 * kg + r) * 256 + jw + 16 * ni + l15];

    // BN partials: 4 quarters each sum 128 of 512 ZSP rows
    {
        const int quarter = tid >> 7, c = tid & 127;
        float s = 0.0f, q = 0.0f;
        for (int b = quarter * 128; b < quarter * 128 + 128; ++b) {
            s += ZSP[(size_t)b * 256 + c];
            q += ZSP[(size_t)b * 256 + 128 + c];
        }
        pS[quarter][c] = s; pQ[quarter][c] = q;
    }
    __syncthreads();
    if (tid < 128) {
        float s = pS[0][tid] + pS[1][tid] + pS[2][tid] + pS[3][tid];
        float q = pQ[0][tid] + pQ[1][tid] + pQ[2][tid] + pQ[3][tid];
        float mu = s * (1.0f / N_);
        float var = q * (1.0f / N_) - mu * mu;
        float aa = rsqrtf(var + EPSF) * bng[tid];
        bnA[tid] = aa;
        bnB[tid] = bnb[tid] - mu * aa;
    }
    __syncthreads();

    // stage Z tile with affine+relu: 16 rows x 16 units = 256 units
    if (tid < 256) {
        int row = tid >> 4, c8 = (tid & 15) * 8;
        const float* zp = Z + (size_t)(i0 + row) * 128 + c8;
        float4 f0 = *(const float4*)zp;
        float4 f1 = *(const float4*)(zp + 4);
        float4 g0, g1;
        g0.x = fmaxf(fmaf(f0.x, bnA[c8 + 0], bnB[c8 + 0]), 0.0f);
        g0.y = fmaxf(fmaf(f0.y, bnA[c8 + 1], bnB[c8 + 1]), 0.0f);
        g0.z = fmaxf(fmaf(f0.z, bnA[c8 + 2], bnB[c8 + 2]), 0.0f);
        g0.w = fmaxf(fmaf(f0.w, bnA[c8 + 3], bnB[c8 + 3]), 0.0f);
        g1.x = fmaxf(fmaf(f1.x, bnA[c8 + 4], bnB[c8 + 4]), 0.0f);
        g1.y = fmaxf(fmaf(f1.y, bnA[c8 + 5], bnB[c8 + 5]), 0.0f);
        g1.z = fmaxf(fmaf(f1.z, bnA[c8 + 6], bnB[c8 + 6]), 0.0f);
        g1.w = fmaxf(fmaf(f1.w, bnA[c8 + 7], bnB[c8 + 7]), 0.0f);
        *(bf16x8*)(&XS[row][c8]) = cvt8(g0, g1);
    }
    __syncthreads();

    f32x4 acc[2];
    acc[0] = 0.0f; acc[1] = 0.0f;

    for (int k0 = 0; k0 < 128; k0 += 32) {
        bf16x8 a = *(const bf16x8*)(&XS[l15][k0 + 8 * kg]);
        bf16x8 b[2];
#pragma unroll
        for (int ni = 0; ni < 2; ++ni) {
            const float* p = W + (size_t)(jw + 16 * ni + l15) * 128 + k0 + 8 * kg;
            b[ni] = cvt8(*(const float4*)p, *(const float4*)(p + 4));
        }
#pragma unroll
        for (int ni = 0; ni < 2; ++ni)
            acc[ni] = __builtin_amdgcn_mfma_f32_16x16x32_bf16(a, b[ni], acc[ni], 0, 0, 0);
    }

#pragma unroll
    for (int ni = 0; ni < 2; ++ni)
#pragma unroll
        for (int r = 0; r < 4; ++r) {
            const size_t idx = (size_t)(i0 + 4 * kg + r) * 256
                             + (jw + 16 * ni + l15);
            out[idx] = oprev[ni][r] + acc[ni][r];
        }
}

// ---------------------------------------------------------------------------
extern "C" void kernel_launch(void* const* d_in, const int* in_sizes, int n_in,
                              void* d_out, int out_size, void* d_ws, size_t ws_size,
                              hipStream_t stream)
{
    const float* x    = (const float*)d_in[0];
    const float* wq   = (const float*)d_in[1];
    const float* bq   = (const float*)d_in[2];
    const float* wk   = (const float*)d_in[3];
    const float* bk   = (const float*)d_in[4];
    const float* wv   = (const float*)d_in[5];
    const float* bv   = (const float*)d_in[6];
    const float* cw   = (const float*)d_in[7];
    const float* cb   = (const float*)d_in[8];
    const float* m1w  = (const float*)d_in[9];
    const float* m2w  = (const float*)d_in[10];
    const float* bng  = (const float*)d_in[11];
    const float* bnb  = (const float*)d_in[12];
    const float* ln1g = (const float*)d_in[13];
    const float* ln1b = (const float*)d_in[14];
    const float* ln2g = (const float*)d_in[15];
    const float* ln2b = (const float*)d_in[16];

    float* outF = (float*)d_out;
    char*  wsb  = (char*)d_ws;
    if (ws_size < WS_NEED) return;

    ushort_t* QbG = (ushort_t*)(wsb + OFF_QB);
    ushort_t* KT  = (ushort_t*)(wsb + OFF_KT);
    ushort_t* VT  = (ushort_t*)(wsb + OFF_VT);
    float*    GP  = (float*)(wsb + OFF_GP);
    ushort_t* MT  = (ushort_t*)(wsb + OFF_MT);
    float*    SVP = (float*)(wsb + OFF_SVP);
    float*    SVC = (float*)(wsb + OFF_SVC);
    float*    RED = (float*)(wsb + OFF_RED);
    float*    ZSP = (float*)(wsb + OFF_ZSP);
    float*    Z   = (float*)(wsb + OFF_GP);   // GP dead after combine_m

    const dim3 b256(256);
    const dim3 b512(512);

    qkv_mfma<<<dim3(256, 3), b256, 0, stream>>>(x, wq, bq, wk, bk, wv, bv,
                                                QbG, KT, VT, RED, SVP);
    g_mfma<<<dim3(4, 4, 16), b256, 0, stream>>>(KT, VT, GP);
    combine_m<<<256, b256, 0, stream>>>(GP, cw, RED, SVP, cb, MT, SVC);
    attn_ln_z_mfma<<<512, b512, 0, stream>>>(QbG, MT, SVC, x,
                                             ln1g, ln1b, ln2g, ln2b, m1w,
                                             outF, Z, ZSP);
    gemm_out_mfma<<<512, b512, 0, stream>>>(Z, m2w, ZSP, bng, bnb, outF);
}

// Round 14
// 98.317 us; speedup vs baseline: 1.3334x; 1.3334x over previous
//
#include <hip/hip_runtime.h>
#include <hip/hip_bf16.h>
#include <math.h>

// ---------------------------------------------------------------------------
// GraphBased_selfAttnLayer — collapsed attention path, 6 launches.
//
//   G_v  = (S_{v-1} K)^T V            (MFMA, K-dim 8192, VT-layout + alignbit)
//   M_u  = scale * sum_v cw[u][v] G_v   -> MTc fragment-coalesced layout
//   attn = sum_u S_{u-1}(Q M_u) + cb*colsum(V); h = x + LN1(attn);
//   l2 = LN2(h) (LDS only); z = l2@m1w^T (fused) ; BN (2-stage) ;
//   out = h + relu(z*a+b) @ m2w^T
//
// Launches: qkv -> g -> combine -> attn+LN+z -> bn_reduce -> out.
//
// MTc layout: MTc[u][kb][j][e] = M_u[j][ d=kb*8+e ]  (bf16, kb=0..31, e=0..7)
//   -> B-fragment load for MFMA is 16 consecutive 16B chunks (coalesced).
//
// ws (bytes):
//   QbG bf16 [8194][256]   @ 0
//   KT  bf16 [256][8192]   @  4,195,328
//   VT  bf16 [256][8200]   @  8,389,632   (guard cols 0/8193; VT[j][c]=V[c-1][j])
//   GP  f32 [48][256][256] @ 12,588,032   <- after combine: Z f32 [8192][128]
//   MTc bf16 [3][32][256][8] @ 25,170,944
//   SVP f32 [256][256]     @ 25,564,160
//   SVC f32 [256]          @ 25,826,304
//   RED f32 [512]          @ 25,827,328
//   ZSP f32 [512][256]     @ 25,829,376
//   BNS f32 [256]          @ 26,353,664   (ends 26,354,688)
// ---------------------------------------------------------------------------

#define N_ 8192
#define D_ 256
#define H_ 128
#define EPSF 1e-5f

typedef unsigned short ushort_t;
typedef unsigned int uint_t;
typedef __attribute__((ext_vector_type(8))) short bf16x8;
typedef __attribute__((ext_vector_type(4))) short bf16x4;
typedef __attribute__((ext_vector_type(4))) float f32x4;

static const size_t OFF_QB  = 0;
static const size_t OFF_KT  = 4195328;
static const size_t OFF_VT  = 8389632;
static const size_t OFF_GP  = 12588032;
static const size_t OFF_MT  = 25170944;
static const size_t OFF_SVP = 25564160;
static const size_t OFF_SVC = 25826304;
static const size_t OFF_RED = 25827328;
static const size_t OFF_ZSP = 25829376;
static const size_t OFF_BNS = 26353664;
static const size_t WS_NEED = 26354688;

#define VT_S 8200   // VT row stride (elems)

__device__ __forceinline__ ushort_t f2bf(float f) {
    __hip_bfloat16 h = __float2bfloat16(f);
    return reinterpret_cast<ushort_t&>(h);
}

__device__ __forceinline__ bf16x8 cvt8(float4 f0, float4 f1) {
    bf16x8 o;
    o[0] = (short)f2bf(f0.x); o[1] = (short)f2bf(f0.y);
    o[2] = (short)f2bf(f0.z); o[3] = (short)f2bf(f0.w);
    o[4] = (short)f2bf(f1.x); o[5] = (short)f2bf(f1.y);
    o[6] = (short)f2bf(f1.z); o[7] = (short)f2bf(f1.w);
    return o;
}

__device__ __forceinline__ float waveSum(float v)
{
#pragma unroll
    for (int o = 32; o > 0; o >>= 1) v += __shfl_xor(v, o);
    return v;
}

// ---------------------------------------------------------------------------
// qkv via MFMA with LDS-staged operands (proven, unchanged).
// ---------------------------------------------------------------------------
__global__ void __launch_bounds__(256)
qkv_mfma(const float* __restrict__ x,
         const float* __restrict__ wq, const float* __restrict__ bq,
         const float* __restrict__ wk, const float* __restrict__ bk,
         const float* __restrict__ wv, const float* __restrict__ bv,
         ushort_t* __restrict__ QbG, ushort_t* __restrict__ KT,
         ushort_t* __restrict__ VT,
         float* __restrict__ RED, float* __restrict__ SVP)
{
    __shared__ ushort_t XS[32][264];
    __shared__ ushort_t WS[256][40];
    __shared__ float lds4[4];
    const int tid = threadIdx.x, lane = tid & 63, wid = tid >> 6;
    const int sel = blockIdx.y;
    const int i0 = blockIdx.x * 32;
    const int jw = wid * 64;
    const int l15 = lane & 15, kg = lane >> 4;
    const float* W = (sel == 0) ? wq : ((sel == 1) ? wk : wv);
    const float* B = (sel == 0) ? bq : ((sel == 1) ? bk : bv);

    if (sel == 0 && blockIdx.x == 0) {
        QbG[tid] = 0; QbG[(size_t)8193 * 256 + tid] = 0;
        VT[(size_t)tid * VT_S] = 0; VT[(size_t)tid * VT_S + 8193] = 0;
    }

#pragma unroll
    for (int p = 0; p < 4; ++p) {
        int lin = p * 256 + tid;
        int row = lin >> 5;
        int c8  = (lin & 31) * 8;
        const float* xp = x + (size_t)(i0 + row) * 256 + c8;
        *(bf16x8*)(&XS[row][c8]) = cvt8(*(const float4*)xp, *(const float4*)(xp + 4));
    }

    f32x4 acc[2][4];
#pragma unroll
    for (int mi = 0; mi < 2; ++mi)
#pragma unroll
        for (int ni = 0; ni < 4; ++ni) acc[mi][ni] = 0.0f;

    for (int k0 = 0; k0 < 256; k0 += 32) {
        __syncthreads();
#pragma unroll
        for (int p = 0; p < 4; ++p) {
            int j  = p * 64 + (tid >> 2);
            int c8 = (tid & 3) * 8;
            const float* wp = W + (size_t)j * 256 + k0 + c8;
            *(bf16x8*)(&WS[j][c8]) = cvt8(*(const float4*)wp, *(const float4*)(wp + 4));
        }
        __syncthreads();

        bf16x8 a[2], b[4];
#pragma unroll
        for (int mi = 0; mi < 2; ++mi)
            a[mi] = *(const bf16x8*)(&XS[16 * mi + l15][k0 + 8 * kg]);
#pragma unroll
        for (int ni = 0; ni < 4; ++ni)
            b[ni] = *(const bf16x8*)(&WS[jw + 16 * ni + l15][8 * kg]);
#pragma unroll
        for (int mi = 0; mi < 2; ++mi)
#pragma unroll
            for (int ni = 0; ni < 4; ++ni)
                acc[mi][ni] = __builtin_amdgcn_mfma_f32_16x16x32_bf16(a[mi], b[ni], acc[mi][ni], 0, 0, 0);
    }

    float ssq = 0.0f;
    float colp[4] = {0.0f, 0.0f, 0.0f, 0.0f};

    if (sel == 0) {
#pragma unroll
        for (int mi = 0; mi < 2; ++mi)
#pragma unroll
            for (int ni = 0; ni < 4; ++ni) {
                const int col = jw + 16 * ni + l15;
                const float bias = B[col];
#pragma unroll
                for (int r = 0; r < 4; ++r) {
                    const int row = i0 + 16 * mi + 4 * kg + r;
                    float val = acc[mi][ni][r] + bias;
                    QbG[(size_t)(row + 1) * 256 + col] = f2bf(val);
                    ssq = fmaf(val, val, ssq);
                }
            }
    } else if (sel == 1) {
#pragma unroll
        for (int mi = 0; mi < 2; ++mi)
#pragma unroll
            for (int ni = 0; ni < 4; ++ni) {
                const int col = jw + 16 * ni + l15;   // d
                const float bias = B[col];
                const int tb = i0 + 16 * mi + 4 * kg;
                bf16x4 pk;
#pragma unroll
                for (int r = 0; r < 4; ++r) {
                    float val = acc[mi][ni][r] + bias;
                    ssq = fmaf(val, val, ssq);
                    pk[r] = (short)f2bf(val);
                }
                *(bf16x4*)(KT + (size_t)col * 8192 + tb) = pk;
            }
    } else {
#pragma unroll
        for (int mi = 0; mi < 2; ++mi)
#pragma unroll
            for (int ni = 0; ni < 4; ++ni) {
                const int col = jw + 16 * ni + l15;   // j
                const float bias = B[col];
                const int tb = i0 + 16 * mi + 4 * kg;
                float v0 = acc[mi][ni][0] + bias, v1 = acc[mi][ni][1] + bias;
                float v2 = acc[mi][ni][2] + bias, v3 = acc[mi][ni][3] + bias;
                colp[ni] += v0 + v1 + v2 + v3;
                ushort_t* p = VT + (size_t)col * VT_S + tb + 1;
                p[0] = f2bf(v0);
                *(uint_t*)(p + 1) = (uint_t)f2bf(v1) | ((uint_t)f2bf(v2) << 16);
                p[3] = f2bf(v3);
            }
    }

    if (sel < 2) {
        float s = ssq;
#pragma unroll
        for (int o = 32; o > 0; o >>= 1) s += __shfl_down(s, o);
        if (lane == 0) lds4[wid] = s;
        __syncthreads();
        if (tid == 0)
            RED[sel * 256 + blockIdx.x] = lds4[0] + lds4[1] + lds4[2] + lds4[3];
    } else {
#pragma unroll
        for (int ni = 0; ni < 4; ++ni) {
            float v = colp[ni];
            v += __shfl_xor(v, 16);
            v += __shfl_xor(v, 32);
            if (kg == 0)
                SVP[(size_t)blockIdx.x * 256 + jw + 16 * ni + l15] = v;
        }
    }
}

// ---------------------------------------------------------------------------
// G_v[d][j] = sum_t K[t][d] * V[t+1-v][j].  grid (4, 4, 16) = 256 blocks.
// Direct-load version (proven, unchanged).
// ---------------------------------------------------------------------------
__global__ void __launch_bounds__(256)
g_mfma(const ushort_t* __restrict__ KT, const ushort_t* __restrict__ VT,
       float* __restrict__ GP)
{
    const int tid = threadIdx.x, lane = tid & 63, wid = tid >> 6;
    const int d0 = blockIdx.x * 64;
    const int jw = blockIdx.y * 64 + wid * 16;
    const int ks = blockIdx.z;
    const int l15 = lane & 15, kg = lane >> 4;

    f32x4 acc[3][4];
#pragma unroll
    for (int v = 0; v < 3; ++v)
#pragma unroll
        for (int mi = 0; mi < 4; ++mi) acc[v][mi] = 0.0f;

    for (int tt = 0; tt < 512; tt += 32) {
        const int t0 = ks * 512 + tt;
        bf16x8 a[4];
#pragma unroll
        for (int mi = 0; mi < 4; ++mi)
            a[mi] = *(const bf16x8*)(KT + (size_t)(d0 + 16 * mi + l15) * 8192 + t0 + 8 * kg);

        const ushort_t* vp = VT + (size_t)(jw + l15) * VT_S + t0 + 8 * kg;
        uint4 r0 = *(const uint4*)vp;          // cols +0..7 -> v=2
        uint4 r2 = *(const uint4*)(vp + 2);    // cols +2..9 -> v=0
        uint4 m1;
        m1.x = (r0.x >> 16) | (r2.x << 16);
        m1.y = (r0.y >> 16) | (r2.y << 16);
        m1.z = (r0.z >> 16) | (r2.z << 16);
        m1.w = (r0.w >> 16) | (r2.w << 16);    // cols +1..8 -> v=1
        bf16x8 b2 = __builtin_bit_cast(bf16x8, r0);
        bf16x8 b0 = __builtin_bit_cast(bf16x8, r2);
        bf16x8 b1 = __builtin_bit_cast(bf16x8, m1);
#pragma unroll
        for (int mi = 0; mi < 4; ++mi) {
            acc[0][mi] = __builtin_amdgcn_mfma_f32_16x16x32_bf16(a[mi], b0, acc[0][mi], 0, 0, 0);
            acc[1][mi] = __builtin_amdgcn_mfma_f32_16x16x32_bf16(a[mi], b1, acc[1][mi], 0, 0, 0);
            acc[2][mi] = __builtin_amdgcn_mfma_f32_16x16x32_bf16(a[mi], b2, acc[2][mi], 0, 0, 0);
        }
    }

#pragma unroll
    for (int v = 0; v < 3; ++v) {
        float* gp = GP + (size_t)(ks * 3 + v) * 65536;
#pragma unroll
        for (int mi = 0; mi < 4; ++mi)
#pragma unroll
            for (int r = 0; r < 4; ++r)
                gp[(size_t)(d0 + 16 * mi + 4 * kg + r) * 256 + (jw + l15)]
                    = acc[v][mi][r];
    }
}

// ---------------------------------------------------------------------------
// MTc[u][kb][j][e] = scale * sum_v cw[u][v] * sum_ks GP[ks*3+v][d=kb*8+e][j].
// Fragment-coalesced layout so attn's B loads are contiguous per wave.
// ---------------------------------------------------------------------------
__global__ void combine_m(const float* __restrict__ GP, const float* __restrict__ cw,
                          const float* __restrict__ RED, const float* __restrict__ SVP,
                          const float* __restrict__ cb,
                          ushort_t* __restrict__ MTc, float* __restrict__ SVC)
{
    __shared__ float lds8[8];
    __shared__ float scsh;
    const int d = blockIdx.x, j = threadIdx.x;

    float sq = RED[j], sk = RED[256 + j];
#pragma unroll
    for (int o = 32; o > 0; o >>= 1) { sq += __shfl_down(sq, o); sk += __shfl_down(sk, o); }
    if ((j & 63) == 0) { lds8[j >> 6] = sq; lds8[4 + (j >> 6)] = sk; }

    float g[3] = {0.0f, 0.0f, 0.0f};
    for (int ks = 0; ks < 16; ++ks)
#pragma unroll
        for (int v = 0; v < 3; ++v)
            g[v] += GP[(size_t)(ks * 3 + v) * 65536 + (size_t)d * 256 + j];

    __syncthreads();
    if (j == 0) {
        float SQ = lds8[0] + lds8[1] + lds8[2] + lds8[3];
        float SK = lds8[4] + lds8[5] + lds8[6] + lds8[7];
        scsh = rsqrtf(SQ) * rsqrtf(SK);
    }
    __syncthreads();
    const float sc = scsh;

#pragma unroll
    for (int u = 0; u < 3; ++u) {
        float m = sc * (cw[u * 3 + 0] * g[0] + cw[u * 3 + 1] * g[1] + cw[u * 3 + 2] * g[2]);
        MTc[(size_t)u * 65536 + (size_t)(d >> 3) * 2048 + (size_t)j * 8 + (d & 7)]
            = f2bf(m);
    }
    if (d == 0) {
        float s = 0.0f;
        for (int b = 0; b < 256; ++b) s += SVP[(size_t)b * 256 + j];
        SVC[j] = cb[0] * s;
    }
}

// ---------------------------------------------------------------------------
// attn + LN + z fused. 512 threads (8 waves), 16 rows/block, grid 512.
// B loads from MTc are fully coalesced; Q from LDS; x prefetched.
// ---------------------------------------------------------------------------
__global__ void __launch_bounds__(512)
attn_ln_z_mfma(const ushort_t* __restrict__ QbG, const ushort_t* __restrict__ MTc,
               const float* __restrict__ SVC, const float* __restrict__ x,
               const float* __restrict__ ln1g, const float* __restrict__ ln1b,
               const float* __restrict__ ln2g, const float* __restrict__ ln2b,
               const float* __restrict__ m1w,
               float* __restrict__ h, float* __restrict__ Z,
               float* __restrict__ ZSP)
{
    __shared__ ushort_t QS[18][264];
    __shared__ float OUT[16][260];
    __shared__ ushort_t WS[128][40];
    const int tid = threadIdx.x, lane = tid & 63, wid = tid >> 6;  // wid 0..7
    const int i0 = blockIdx.x * 16;
    const int jw = wid * 32;
    const int l15 = lane & 15, kg = lane >> 4;

    // prefetch x for this wave's LN rows (consumed after attention GEMM)
    float4 xpre0 = *(const float4*)(x + (size_t)(i0 + wid * 2 + 0) * 256 + lane * 4);
    float4 xpre1 = *(const float4*)(x + (size_t)(i0 + wid * 2 + 1) * 256 + lane * 4);

    // stage Q tile: 18 rows x 32 units = 576 units over 512 threads
    {
        int row = tid >> 5, c8 = (tid & 31) * 8;
        *(bf16x8*)(&QS[row][c8]) = *(const bf16x8*)(QbG + (size_t)(i0 + row) * 256 + c8);
        int idx = tid + 512;
        if (idx < 576) {
            row = idx >> 5; c8 = (idx & 31) * 8;
            *(bf16x8*)(&QS[row][c8]) = *(const bf16x8*)(QbG + (size_t)(i0 + row) * 256 + c8);
        }
    }
    __syncthreads();

    // ---- 1) attention GEMM: A from LDS, B from MTc (coalesced direct) ----
    f32x4 acc[2];
    acc[0] = 0.0f; acc[1] = 0.0f;

    for (int k0 = 0; k0 < 256; k0 += 32) {
        bf16x8 a[3], b[3][2];
#pragma unroll
        for (int u = 0; u < 3; ++u)
            a[u] = *(const bf16x8*)(&QS[l15 + u][k0 + 8 * kg]);
#pragma unroll
        for (int u = 0; u < 3; ++u)
#pragma unroll
            for (int ni = 0; ni < 2; ++ni)
                b[u][ni] = *(const bf16x8*)(MTc + (size_t)u * 65536
                    + (size_t)((k0 >> 3) + kg) * 2048
                    + (size_t)(jw + 16 * ni + l15) * 8);
#pragma unroll
        for (int ni = 0; ni < 2; ++ni)
#pragma unroll
            for (int u = 0; u < 3; ++u)
                acc[ni] = __builtin_amdgcn_mfma_f32_16x16x32_bf16(
                    a[u], b[u][ni], acc[ni], 0, 0, 0);
    }

#pragma unroll
    for (int ni = 0; ni < 2; ++ni) {
        const int col = jw + 16 * ni + l15;
        const float sv = SVC[col];
#pragma unroll
        for (int r = 0; r < 4; ++r)
            OUT[4 * kg + r][col] = acc[ni][r] + sv;
    }
    __syncthreads();

    // ---- 2) LN (wave-per-row, 2 rows/wave): h -> global, l2 -> OUT ----
    const float4 g14 = *(const float4*)(ln1g + lane * 4);
    const float4 b14 = *(const float4*)(ln1b + lane * 4);
    const float4 g24 = *(const float4*)(ln2g + lane * 4);
    const float4 b24 = *(const float4*)(ln2b + lane * 4);
#pragma unroll
    for (int rr = 0; rr < 2; ++rr) {
        const int row_l = wid * 2 + rr;
        const size_t off = (size_t)(i0 + row_l) * 256 + lane * 4;

        float4 a4 = *(const float4*)&OUT[row_l][lane * 4];
        float m = waveSum(a4.x + a4.y + a4.z + a4.w) * (1.0f / D_);
        float4 d4 = make_float4(a4.x - m, a4.y - m, a4.z - m, a4.w - m);
        float var = waveSum(d4.x * d4.x + d4.y * d4.y + d4.z * d4.z + d4.w * d4.w) * (1.0f / D_);
        float rs = rsqrtf(var + EPSF);

        float4 x4 = (rr == 0) ? xpre0 : xpre1;
        float4 h4;
        h4.x = x4.x + d4.x * rs * g14.x + b14.x;
        h4.y = x4.y + d4.y * rs * g14.y + b14.y;
        h4.z = x4.z + d4.z * rs * g14.z + b14.z;
        h4.w = x4.w + d4.w * rs * g14.w + b14.w;
        *(float4*)(h + off) = h4;

        float m2 = waveSum(h4.x + h4.y + h4.z + h4.w) * (1.0f / D_);
        float4 e4 = make_float4(h4.x - m2, h4.y - m2, h4.z - m2, h4.w - m2);
        float v2 = waveSum(e4.x * e4.x + e4.y * e4.y + e4.z * e4.z + e4.w * e4.w) * (1.0f / D_);
        float rs2 = rsqrtf(v2 + EPSF);

        float4 o4;
        o4.x = e4.x * rs2 * g24.x + b24.x;
        o4.y = e4.y * rs2 * g24.y + b24.y;
        o4.z = e4.z * rs2 * g24.z + b24.z;
        o4.w = e4.w * rs2 * g24.w + b24.w;
        *(float4*)&OUT[row_l][lane * 4] = o4;   // l2 stays in LDS
    }
    __syncthreads();

    // ---- 3) z = l2 @ m1w^T from LDS; 8 waves each own 16 of 128 cols ----
    const int jz = wid * 16;
    f32x4 zacc;
    zacc = 0.0f;

    for (int k0 = 0; k0 < 256; k0 += 32) {
        if (k0) __syncthreads();
        {
            int j  = tid >> 2;
            int c8 = (tid & 3) * 8;
            const float* wp = m1w + (size_t)j * 256 + k0 + c8;
            *(bf16x8*)(&WS[j][c8]) = cvt8(*(const float4*)wp, *(const float4*)(wp + 4));
        }
        __syncthreads();

        bf16x8 a, b;
        {
            const float* lp = &OUT[l15][k0 + 8 * kg];
            a = cvt8(*(const float4*)lp, *(const float4*)(lp + 4));
        }
        b = *(const bf16x8*)(&WS[jz + l15][8 * kg]);
        zacc = __builtin_amdgcn_mfma_f32_16x16x32_bf16(a, b, zacc, 0, 0, 0);
    }

    float s = 0.0f, q = 0.0f;
    const int col = jz + l15;
#pragma unroll
    for (int r = 0; r < 4; ++r) {
        float zv = zacc[r];
        Z[(size_t)(i0 + 4 * kg + r) * 128 + col] = zv;
        s += zv;
        q = fmaf(zv, zv, q);
    }
    s += __shfl_xor(s, 16); s += __shfl_xor(s, 32);
    q += __shfl_xor(q, 16); q += __shfl_xor(q, 32);
    if (kg == 0) {
        ZSP[(size_t)blockIdx.x * 256 + col] = s;
        ZSP[(size_t)blockIdx.x * 256 + 128 + col] = q;
    }
}

// ---------------------------------------------------------------------------
// bn_reduce: BNS[c] = sum_b ZSP[b][c]  (c: 0..127 = colsum, 128..255 = sumsq)
// grid 8 x 256 threads; deterministic two-level reduction.
// ---------------------------------------------------------------------------
__global__ void bn_reduce(const float* __restrict__ ZSP, float* __restrict__ BNS)
{
    __shared__ float red[8][32];
    const int tid = threadIdx.x;
    const int c0 = blockIdx.x * 32;
    const int cl = tid & 31, g = tid >> 5;   // 8 row-groups
    float s = 0.0f;
    for (int b = g; b < 512; b += 8)
        s += ZSP[(size_t)b * 256 + c0 + cl];
    red[g][cl] = s;
    __syncthreads();
    if (tid < 32) {
        float t = 0.0f;
#pragma unroll
        for (int g2 = 0; g2 < 8; ++g2) t += red[g2][tid];
        BNS[c0 + tid] = t;
    }
}

// ---------------------------------------------------------------------------
// out = h + relu(z*a+b) @ m2w^T. 512 threads, 16 rows, grid 512.
// BN affine from BNS (2 loads); Z tile staged with affine+relu;
// m2w LDS-staged per k-chunk (kills row-stride amplification);
// out RMW addend prefetched at entry.
// ---------------------------------------------------------------------------
__global__ void __launch_bounds__(512)
gemm_out_mfma(const float* __restrict__ Z, const float* __restrict__ W,
              const float* __restrict__ BNS,
              const float* __restrict__ bng, const float* __restrict__ bnb,
              float* __restrict__ out)
{
    __shared__ float bnA[128], bnB[128];
    __shared__ ushort_t XS[16][136];
    __shared__ ushort_t WS2[256][40];
    const int tid = threadIdx.x, lane = tid & 63, wid = tid >> 6;  // 0..7
    const int i0 = blockIdx.x * 16;
    const int jw = wid * 32;
    const int l15 = lane & 15, kg = lane >> 4;

    // prefetch out RMW addend (h values) — consumed in epilogue
    float oprev[2][4];
#pragma unroll
    for (int ni = 0; ni < 2; ++ni)
#pragma unroll
        for (int r = 0; r < 4; ++r)
            oprev[ni][r] = out[(size_t)(i0 + 4 * kg + r) * 256 + jw + 16 * ni + l15];

    if (tid < 128) {
        float s = BNS[tid], q = BNS[128 + tid];
        float mu = s * (1.0f / N_);
        float var = q * (1.0f / N_) - mu * mu;
        float aa = rsqrtf(var + EPSF) * bng[tid];
        bnA[tid] = aa;
        bnB[tid] = bnb[tid] - mu * aa;
    }
    __syncthreads();

    // stage Z tile with affine+relu: 16 rows x 16 units = 256 units
    if (tid < 256) {
        int row = tid >> 4, c8 = (tid & 15) * 8;
        const float* zp = Z + (size_t)(i0 + row) * 128 + c8;
        float4 f0 = *(const float4*)zp;
        float4 f1 = *(const float4*)(zp + 4);
        float4 g0, g1;
        g0.x = fmaxf(fmaf(f0.x, bnA[c8 + 0], bnB[c8 + 0]), 0.0f);
        g0.y = fmaxf(fmaf(f0.y, bnA[c8 + 1], bnB[c8 + 1]), 0.0f);
        g0.z = fmaxf(fmaf(f0.z, bnA[c8 + 2], bnB[c8 + 2]), 0.0f);
        g0.w = fmaxf(fmaf(f0.w, bnA[c8 + 3], bnB[c8 + 3]), 0.0f);
        g1.x = fmaxf(fmaf(f1.x, bnA[c8 + 4], bnB[c8 + 4]), 0.0f);
        g1.y = fmaxf(fmaf(f1.y, bnA[c8 + 5], bnB[c8 + 5]), 0.0f);
        g1.z = fmaxf(fmaf(f1.z, bnA[c8 + 6], bnB[c8 + 6]), 0.0f);
        g1.w = fmaxf(fmaf(f1.w, bnA[c8 + 7], bnB[c8 + 7]), 0.0f);
        *(bf16x8*)(&XS[row][c8]) = cvt8(g0, g1);
    }

    f32x4 acc[2];
    acc[0] = 0.0f; acc[1] = 0.0f;

    for (int k0 = 0; k0 < 128; k0 += 32) {
        __syncthreads();
        // stage m2w chunk: 256 rows x 4 units = 1024 units over 512 thr
#pragma unroll
        for (int p = 0; p < 2; ++p) {
            int idx = p * 512 + tid;
            int j  = idx >> 2;
            int c8 = (idx & 3) * 8;
            const float* wp = W + (size_t)j * 128 + k0 + c8;
            *(bf16x8*)(&WS2[j][c8]) = cvt8(*(const float4*)wp, *(const float4*)(wp + 4));
        }
        __syncthreads();

        bf16x8 a = *(const bf16x8*)(&XS[l15][k0 + 8 * kg]);
        bf16x8 b[2];
#pragma unroll
        for (int ni = 0; ni < 2; ++ni)
            b[ni] = *(const bf16x8*)(&WS2[jw + 16 * ni + l15][8 * kg]);
#pragma unroll
        for (int ni = 0; ni < 2; ++ni)
            acc[ni] = __builtin_amdgcn_mfma_f32_16x16x32_bf16(a, b[ni], acc[ni], 0, 0, 0);
    }

#pragma unroll
    for (int ni = 0; ni < 2; ++ni)
#pragma unroll
        for (int r = 0; r < 4; ++r) {
            const size_t idx = (size_t)(i0 + 4 * kg + r) * 256
                             + (jw + 16 * ni + l15);
            out[idx] = oprev[ni][r] + acc[ni][r];
        }
}

// ---------------------------------------------------------------------------
extern "C" void kernel_launch(void* const* d_in, const int* in_sizes, int n_in,
                              void* d_out, int out_size, void* d_ws, size_t ws_size,
                              hipStream_t stream)
{
    const float* x    = (const float*)d_in[0];
    const float* wq   = (const float*)d_in[1];
    const float* bq   = (const float*)d_in[2];
    const float* wk   = (const float*)d_in[3];
    const float* bk   = (const float*)d_in[4];
    const float* wv   = (const float*)d_in[5];
    const float* bv   = (const float*)d_in[6];
    const float* cw   = (const float*)d_in[7];
    const float* cb   = (const float*)d_in[8];
    const float* m1w  = (const float*)d_in[9];
    const float* m2w  = (const float*)d_in[10];
    const float* bng  = (const float*)d_in[11];
    const float* bnb  = (const float*)d_in[12];
    const float* ln1g = (const float*)d_in[13];
    const float* ln1b = (const float*)d_in[14];
    const float* ln2g = (const float*)d_in[15];
    const float* ln2b = (const float*)d_in[16];

    float* outF = (float*)d_out;
    char*  wsb  = (char*)d_ws;
    if (ws_size < WS_NEED) return;

    ushort_t* QbG = (ushort_t*)(wsb + OFF_QB);
    ushort_t* KT  = (ushort_t*)(wsb + OFF_KT);
    ushort_t* VT  = (ushort_t*)(wsb + OFF_VT);
    float*    GP  = (float*)(wsb + OFF_GP);
    ushort_t* MTc = (ushort_t*)(wsb + OFF_MT);
    float*    SVP = (float*)(wsb + OFF_SVP);
    float*    SVC = (float*)(wsb + OFF_SVC);
    float*    RED = (float*)(wsb + OFF_RED);
    float*    ZSP = (float*)(wsb + OFF_ZSP);
    float*    BNS = (float*)(wsb + OFF_BNS);
    float*    Z   = (float*)(wsb + OFF_GP);   // GP dead after combine_m

    const dim3 b256(256);
    const dim3 b512(512);

    qkv_mfma<<<dim3(256, 3), b256, 0, stream>>>(x, wq, bq, wk, bk, wv, bv,
                                                QbG, KT, VT, RED, SVP);
    g_mfma<<<dim3(4, 4, 16), b256, 0, stream>>>(KT, VT, GP);
    combine_m<<<256, b256, 0, stream>>>(GP, cw, RED, SVP, cb, MTc, SVC);
    attn_ln_z_mfma<<<512, b512, 0, stream>>>(QbG, MTc, SVC, x,
                                             ln1g, ln1b, ln2g, ln2b, m1w,
                                             outF, Z, ZSP);
    bn_reduce<<<8, b256, 0, stream>>>(ZSP, BNS);
    gemm_out_mfma<<<512, b512, 0, stream>>>(Z, m2w, BNS, bng, bnb, outF);
}

// Round 15
// 94.356 us; speedup vs baseline: 1.3894x; 1.0420x over previous
//
#include <hip/hip_runtime.h>
#include <hip/hip_bf16.h>
#include <math.h>

// ---------------------------------------------------------------------------
// GraphBased_selfAttnLayer — collapsed attention path, 6 launches.
//
//   G_v  = (S_{v-1} K)^T V            (MFMA, K-dim 8192, VT-layout + alignbit)
//   M_u  = scale * sum_v cw[u][v] G_v   -> MTc fragment-coalesced layout
//   attn = sum_u S_{u-1}(Q M_u) + cb*colsum(V); h = x + LN1(attn);
//   l2 = LN2(h) (LDS only); z = l2@m1w^T (fused) ; BN (2-stage) ;
//   out = h + relu(z*a+b) @ m2w^T
//
// Launches: qkv -> g (512 blocks) -> combine -> attn+LN+z -> bn_reduce -> out.
//
// ws (bytes):
//   QbG bf16 [8194][256]   @ 0
//   KT  bf16 [256][8192]   @  4,195,328
//   VT  bf16 [256][8200]   @  8,389,632   (guard cols 0/8193; VT[j][c]=V[c-1][j])
//   GP  f32 [48][256][256] @ 12,588,032   <- after combine: Z f32 [8192][128]
//   MTc bf16 [3][32][256][8] @ 25,170,944
//   SVP f32 [256][256]     @ 25,564,160
//   SVC f32 [256]          @ 25,826,304
//   RED f32 [512]          @ 25,827,328
//   ZSP f32 [512][256]     @ 25,829,376
//   BNS f32 [256]          @ 26,353,664   (ends 26,354,688)
// ---------------------------------------------------------------------------

#define N_ 8192
#define D_ 256
#define H_ 128
#define EPSF 1e-5f

typedef unsigned short ushort_t;
typedef unsigned int uint_t;
typedef __attribute__((ext_vector_type(8))) short bf16x8;
typedef __attribute__((ext_vector_type(4))) short bf16x4;
typedef __attribute__((ext_vector_type(4))) float f32x4;

static const size_t OFF_QB  = 0;
static const size_t OFF_KT  = 4195328;
static const size_t OFF_VT  = 8389632;
static const size_t OFF_GP  = 12588032;
static const size_t OFF_MT  = 25170944;
static const size_t OFF_SVP = 25564160;
static const size_t OFF_SVC = 25826304;
static const size_t OFF_RED = 25827328;
static const size_t OFF_ZSP = 25829376;
static const size_t OFF_BNS = 26353664;
static const size_t WS_NEED = 26354688;

#define VT_S 8200   // VT row stride (elems)

__device__ __forceinline__ ushort_t f2bf(float f) {
    __hip_bfloat16 h = __float2bfloat16(f);
    return reinterpret_cast<ushort_t&>(h);
}

__device__ __forceinline__ bf16x8 cvt8(float4 f0, float4 f1) {
    bf16x8 o;
    o[0] = (short)f2bf(f0.x); o[1] = (short)f2bf(f0.y);
    o[2] = (short)f2bf(f0.z); o[3] = (short)f2bf(f0.w);
    o[4] = (short)f2bf(f1.x); o[5] = (short)f2bf(f1.y);
    o[6] = (short)f2bf(f1.z); o[7] = (short)f2bf(f1.w);
    return o;
}

__device__ __forceinline__ float waveSum(float v)
{
#pragma unroll
    for (int o = 32; o > 0; o >>= 1) v += __shfl_xor(v, o);
    return v;
}

// ---------------------------------------------------------------------------
// qkv via MFMA with LDS-staged operands (proven, unchanged).
// ---------------------------------------------------------------------------
__global__ void __launch_bounds__(256)
qkv_mfma(const float* __restrict__ x,
         const float* __restrict__ wq, const float* __restrict__ bq,
         const float* __restrict__ wk, const float* __restrict__ bk,
         const float* __restrict__ wv, const float* __restrict__ bv,
         ushort_t* __restrict__ QbG, ushort_t* __restrict__ KT,
         ushort_t* __restrict__ VT,
         float* __restrict__ RED, float* __restrict__ SVP)
{
    __shared__ ushort_t XS[32][264];
    __shared__ ushort_t WS[256][40];
    __shared__ float lds4[4];
    const int tid = threadIdx.x, lane = tid & 63, wid = tid >> 6;
    const int sel = blockIdx.y;
    const int i0 = blockIdx.x * 32;
    const int jw = wid * 64;
    const int l15 = lane & 15, kg = lane >> 4;
    const float* W = (sel == 0) ? wq : ((sel == 1) ? wk : wv);
    const float* B = (sel == 0) ? bq : ((sel == 1) ? bk : bv);

    if (sel == 0 && blockIdx.x == 0) {
        QbG[tid] = 0; QbG[(size_t)8193 * 256 + tid] = 0;
        VT[(size_t)tid * VT_S] = 0; VT[(size_t)tid * VT_S + 8193] = 0;
    }

#pragma unroll
    for (int p = 0; p < 4; ++p) {
        int lin = p * 256 + tid;
        int row = lin >> 5;
        int c8  = (lin & 31) * 8;
        const float* xp = x + (size_t)(i0 + row) * 256 + c8;
        *(bf16x8*)(&XS[row][c8]) = cvt8(*(const float4*)xp, *(const float4*)(xp + 4));
    }

    f32x4 acc[2][4];
#pragma unroll
    for (int mi = 0; mi < 2; ++mi)
#pragma unroll
        for (int ni = 0; ni < 4; ++ni) acc[mi][ni] = 0.0f;

    for (int k0 = 0; k0 < 256; k0 += 32) {
        __syncthreads();
#pragma unroll
        for (int p = 0; p < 4; ++p) {
            int j  = p * 64 + (tid >> 2);
            int c8 = (tid & 3) * 8;
            const float* wp = W + (size_t)j * 256 + k0 + c8;
            *(bf16x8*)(&WS[j][c8]) = cvt8(*(const float4*)wp, *(const float4*)(wp + 4));
        }
        __syncthreads();

        bf16x8 a[2], b[4];
#pragma unroll
        for (int mi = 0; mi < 2; ++mi)
            a[mi] = *(const bf16x8*)(&XS[16 * mi + l15][k0 + 8 * kg]);
#pragma unroll
        for (int ni = 0; ni < 4; ++ni)
            b[ni] = *(const bf16x8*)(&WS[jw + 16 * ni + l15][8 * kg]);
#pragma unroll
        for (int mi = 0; mi < 2; ++mi)
#pragma unroll
            for (int ni = 0; ni < 4; ++ni)
                acc[mi][ni] = __builtin_amdgcn_mfma_f32_16x16x32_bf16(a[mi], b[ni], acc[mi][ni], 0, 0, 0);
    }

    float ssq = 0.0f;
    float colp[4] = {0.0f, 0.0f, 0.0f, 0.0f};

    if (sel == 0) {
#pragma unroll
        for (int mi = 0; mi < 2; ++mi)
#pragma unroll
            for (int ni = 0; ni < 4; ++ni) {
                const int col = jw + 16 * ni + l15;
                const float bias = B[col];
#pragma unroll
                for (int r = 0; r < 4; ++r) {
                    const int row = i0 + 16 * mi + 4 * kg + r;
                    float val = acc[mi][ni][r] + bias;
                    QbG[(size_t)(row + 1) * 256 + col] = f2bf(val);
                    ssq = fmaf(val, val, ssq);
                }
            }
    } else if (sel == 1) {
#pragma unroll
        for (int mi = 0; mi < 2; ++mi)
#pragma unroll
            for (int ni = 0; ni < 4; ++ni) {
                const int col = jw + 16 * ni + l15;   // d
                const float bias = B[col];
                const int tb = i0 + 16 * mi + 4 * kg;
                bf16x4 pk;
#pragma unroll
                for (int r = 0; r < 4; ++r) {
                    float val = acc[mi][ni][r] + bias;
                    ssq = fmaf(val, val, ssq);
                    pk[r] = (short)f2bf(val);
                }
                *(bf16x4*)(KT + (size_t)col * 8192 + tb) = pk;
            }
    } else {
#pragma unroll
        for (int mi = 0; mi < 2; ++mi)
#pragma unroll
            for (int ni = 0; ni < 4; ++ni) {
                const int col = jw + 16 * ni + l15;   // j
                const float bias = B[col];
                const int tb = i0 + 16 * mi + 4 * kg;
                float v0 = acc[mi][ni][0] + bias, v1 = acc[mi][ni][1] + bias;
                float v2 = acc[mi][ni][2] + bias, v3 = acc[mi][ni][3] + bias;
                colp[ni] += v0 + v1 + v2 + v3;
                ushort_t* p = VT + (size_t)col * VT_S + tb + 1;
                p[0] = f2bf(v0);
                *(uint_t*)(p + 1) = (uint_t)f2bf(v1) | ((uint_t)f2bf(v2) << 16);
                p[3] = f2bf(v3);
            }
    }

    if (sel < 2) {
        float s = ssq;
#pragma unroll
        for (int o = 32; o > 0; o >>= 1) s += __shfl_down(s, o);
        if (lane == 0) lds4[wid] = s;
        __syncthreads();
        if (tid == 0)
            RED[sel * 256 + blockIdx.x] = lds4[0] + lds4[1] + lds4[2] + lds4[3];
    } else {
#pragma unroll
        for (int ni = 0; ni < 4; ++ni) {
            float v = colp[ni];
            v += __shfl_xor(v, 16);
            v += __shfl_xor(v, 32);
            if (kg == 0)
                SVP[(size_t)blockIdx.x * 256 + jw + 16 * ni + l15] = v;
        }
    }
}

// ---------------------------------------------------------------------------
// G_v[d][j] = sum_t K[t][d] * V[t+1-v][j].  grid (4, 8, 16) = 512 blocks.
// Block: 64d x 32j; 4 waves: (wid>>1)=d-half (2 mi), (wid&1)=j-half (16 j).
// 2 blocks/CU for latency hiding; A-redundancy 4x -> 2x; regs halved.
// ---------------------------------------------------------------------------
__global__ void __launch_bounds__(256)
g_mfma(const ushort_t* __restrict__ KT, const ushort_t* __restrict__ VT,
       float* __restrict__ GP)
{
    const int tid = threadIdx.x, lane = tid & 63, wid = tid >> 6;
    const int d0 = blockIdx.x * 64 + (wid >> 1) * 32;
    const int jw = blockIdx.y * 32 + (wid & 1) * 16;
    const int ks = blockIdx.z;
    const int l15 = lane & 15, kg = lane >> 4;

    f32x4 acc[3][2];
#pragma unroll
    for (int v = 0; v < 3; ++v) { acc[v][0] = 0.0f; acc[v][1] = 0.0f; }

    for (int tt = 0; tt < 512; tt += 32) {
        const int t0 = ks * 512 + tt;
        bf16x8 a[2];
#pragma unroll
        for (int mi = 0; mi < 2; ++mi)
            a[mi] = *(const bf16x8*)(KT + (size_t)(d0 + 16 * mi + l15) * 8192 + t0 + 8 * kg);

        const ushort_t* vp = VT + (size_t)(jw + l15) * VT_S + t0 + 8 * kg;
        uint4 r0 = *(const uint4*)vp;          // cols +0..7 -> v=2
        uint4 r2 = *(const uint4*)(vp + 2);    // cols +2..9 -> v=0
        uint4 m1;
        m1.x = (r0.x >> 16) | (r2.x << 16);
        m1.y = (r0.y >> 16) | (r2.y << 16);
        m1.z = (r0.z >> 16) | (r2.z << 16);
        m1.w = (r0.w >> 16) | (r2.w << 16);    // cols +1..8 -> v=1
        bf16x8 b2 = __builtin_bit_cast(bf16x8, r0);
        bf16x8 b0 = __builtin_bit_cast(bf16x8, r2);
        bf16x8 b1 = __builtin_bit_cast(bf16x8, m1);
#pragma unroll
        for (int mi = 0; mi < 2; ++mi) {
            acc[0][mi] = __builtin_amdgcn_mfma_f32_16x16x32_bf16(a[mi], b0, acc[0][mi], 0, 0, 0);
            acc[1][mi] = __builtin_amdgcn_mfma_f32_16x16x32_bf16(a[mi], b1, acc[1][mi], 0, 0, 0);
            acc[2][mi] = __builtin_amdgcn_mfma_f32_16x16x32_bf16(a[mi], b2, acc[2][mi], 0, 0, 0);
        }
    }

#pragma unroll
    for (int v = 0; v < 3; ++v) {
        float* gp = GP + (size_t)(ks * 3 + v) * 65536;
#pragma unroll
        for (int mi = 0; mi < 2; ++mi)
#pragma unroll
            for (int r = 0; r < 4; ++r)
                gp[(size_t)(d0 + 16 * mi + 4 * kg + r) * 256 + (jw + l15)]
                    = acc[v][mi][r];
    }
}

// ---------------------------------------------------------------------------
// MTc[u][kb][j][e] = scale * sum_v cw[u][v] * sum_ks GP[ks*3+v][d=kb*8+e][j].
// (unchanged)
// ---------------------------------------------------------------------------
__global__ void combine_m(const float* __restrict__ GP, const float* __restrict__ cw,
                          const float* __restrict__ RED, const float* __restrict__ SVP,
                          const float* __restrict__ cb,
                          ushort_t* __restrict__ MTc, float* __restrict__ SVC)
{
    __shared__ float lds8[8];
    __shared__ float scsh;
    const int d = blockIdx.x, j = threadIdx.x;

    float sq = RED[j], sk = RED[256 + j];
#pragma unroll
    for (int o = 32; o > 0; o >>= 1) { sq += __shfl_down(sq, o); sk += __shfl_down(sk, o); }
    if ((j & 63) == 0) { lds8[j >> 6] = sq; lds8[4 + (j >> 6)] = sk; }

    float g[3] = {0.0f, 0.0f, 0.0f};
    for (int ks = 0; ks < 16; ++ks)
#pragma unroll
        for (int v = 0; v < 3; ++v)
            g[v] += GP[(size_t)(ks * 3 + v) * 65536 + (size_t)d * 256 + j];

    __syncthreads();
    if (j == 0) {
        float SQ = lds8[0] + lds8[1] + lds8[2] + lds8[3];
        float SK = lds8[4] + lds8[5] + lds8[6] + lds8[7];
        scsh = rsqrtf(SQ) * rsqrtf(SK);
    }
    __syncthreads();
    const float sc = scsh;

#pragma unroll
    for (int u = 0; u < 3; ++u) {
        float m = sc * (cw[u * 3 + 0] * g[0] + cw[u * 3 + 1] * g[1] + cw[u * 3 + 2] * g[2]);
        MTc[(size_t)u * 65536 + (size_t)(d >> 3) * 2048 + (size_t)j * 8 + (d & 7)]
            = f2bf(m);
    }
    if (d == 0) {
        float s = 0.0f;
        for (int b = 0; b < 256; ++b) s += SVP[(size_t)b * 256 + j];
        SVC[j] = cb[0] * s;
    }
}

// ---------------------------------------------------------------------------
// attn + LN + z fused. 512 threads (8 waves), 16 rows/block, grid 512.
// (unchanged from round 14)
// ---------------------------------------------------------------------------
__global__ void __launch_bounds__(512)
attn_ln_z_mfma(const ushort_t* __restrict__ QbG, const ushort_t* __restrict__ MTc,
               const float* __restrict__ SVC, const float* __restrict__ x,
               const float* __restrict__ ln1g, const float* __restrict__ ln1b,
               const float* __restrict__ ln2g, const float* __restrict__ ln2b,
               const float* __restrict__ m1w,
               float* __restrict__ h, float* __restrict__ Z,
               float* __restrict__ ZSP)
{
    __shared__ ushort_t QS[18][264];
    __shared__ float OUT[16][260];
    __shared__ ushort_t WS[128][40];
    const int tid = threadIdx.x, lane = tid & 63, wid = tid >> 6;  // wid 0..7
    const int i0 = blockIdx.x * 16;
    const int jw = wid * 32;
    const int l15 = lane & 15, kg = lane >> 4;

    float4 xpre0 = *(const float4*)(x + (size_t)(i0 + wid * 2 + 0) * 256 + lane * 4);
    float4 xpre1 = *(const float4*)(x + (size_t)(i0 + wid * 2 + 1) * 256 + lane * 4);

    {
        int row = tid >> 5, c8 = (tid & 31) * 8;
        *(bf16x8*)(&QS[row][c8]) = *(const bf16x8*)(QbG + (size_t)(i0 + row) * 256 + c8);
        int idx = tid + 512;
        if (idx < 576) {
            row = idx >> 5; c8 = (idx & 31) * 8;
            *(bf16x8*)(&QS[row][c8]) = *(const bf16x8*)(QbG + (size_t)(i0 + row) * 256 + c8);
        }
    }
    __syncthreads();

    f32x4 acc[2];
    acc[0] = 0.0f; acc[1] = 0.0f;

    for (int k0 = 0; k0 < 256; k0 += 32) {
        bf16x8 a[3], b[3][2];
#pragma unroll
        for (int u = 0; u < 3; ++u)
            a[u] = *(const bf16x8*)(&QS[l15 + u][k0 + 8 * kg]);
#pragma unroll
        for (int u = 0; u < 3; ++u)
#pragma unroll
            for (int ni = 0; ni < 2; ++ni)
                b[u][ni] = *(const bf16x8*)(MTc + (size_t)u * 65536
                    + (size_t)((k0 >> 3) + kg) * 2048
                    + (size_t)(jw + 16 * ni + l15) * 8);
#pragma unroll
        for (int ni = 0; ni < 2; ++ni)
#pragma unroll
            for (int u = 0; u < 3; ++u)
                acc[ni] = __builtin_amdgcn_mfma_f32_16x16x32_bf16(
                    a[u], b[u][ni], acc[ni], 0, 0, 0);
    }

#pragma unroll
    for (int ni = 0; ni < 2; ++ni) {
        const int col = jw + 16 * ni + l15;
        const float sv = SVC[col];
#pragma unroll
        for (int r = 0; r < 4; ++r)
            OUT[4 * kg + r][col] = acc[ni][r] + sv;
    }
    __syncthreads();

    const float4 g14 = *(const float4*)(ln1g + lane * 4);
    const float4 b14 = *(const float4*)(ln1b + lane * 4);
    const float4 g24 = *(const float4*)(ln2g + lane * 4);
    const float4 b24 = *(const float4*)(ln2b + lane * 4);
#pragma unroll
    for (int rr = 0; rr < 2; ++rr) {
        const int row_l = wid * 2 + rr;
        const size_t off = (size_t)(i0 + row_l) * 256 + lane * 4;

        float4 a4 = *(const float4*)&OUT[row_l][lane * 4];
        float m = waveSum(a4.x + a4.y + a4.z + a4.w) * (1.0f / D_);
        float4 d4 = make_float4(a4.x - m, a4.y - m, a4.z - m, a4.w - m);
        float var = waveSum(d4.x * d4.x + d4.y * d4.y + d4.z * d4.z + d4.w * d4.w) * (1.0f / D_);
        float rs = rsqrtf(var + EPSF);

        float4 x4 = (rr == 0) ? xpre0 : xpre1;
        float4 h4;
        h4.x = x4.x + d4.x * rs * g14.x + b14.x;
        h4.y = x4.y + d4.y * rs * g14.y + b14.y;
        h4.z = x4.z + d4.z * rs * g14.z + b14.z;
        h4.w = x4.w + d4.w * rs * g14.w + b14.w;
        *(float4*)(h + off) = h4;

        float m2 = waveSum(h4.x + h4.y + h4.z + h4.w) * (1.0f / D_);
        float4 e4 = make_float4(h4.x - m2, h4.y - m2, h4.z - m2, h4.w - m2);
        float v2 = waveSum(e4.x * e4.x + e4.y * e4.y + e4.z * e4.z + e4.w * e4.w) * (1.0f / D_);
        float rs2 = rsqrtf(v2 + EPSF);

        float4 o4;
        o4.x = e4.x * rs2 * g24.x + b24.x;
        o4.y = e4.y * rs2 * g24.y + b24.y;
        o4.z = e4.z * rs2 * g24.z + b24.z;
        o4.w = e4.w * rs2 * g24.w + b24.w;
        *(float4*)&OUT[row_l][lane * 4] = o4;
    }
    __syncthreads();

    const int jz = wid * 16;
    f32x4 zacc;
    zacc = 0.0f;

    for (int k0 = 0; k0 < 256; k0 += 32) {
        if (k0) __syncthreads();
        {
            int j  = tid >> 2;
            int c8 = (tid & 3) * 8;
            const float* wp = m1w + (size_t)j * 256 + k0 + c8;
            *(bf16x8*)(&WS[j][c8]) = cvt8(*(const float4*)wp, *(const float4*)(wp + 4));
        }
        __syncthreads();

        bf16x8 a, b;
        {
            const float* lp = &OUT[l15][k0 + 8 * kg];
            a = cvt8(*(const float4*)lp, *(const float4*)(lp + 4));
        }
        b = *(const bf16x8*)(&WS[jz + l15][8 * kg]);
        zacc = __builtin_amdgcn_mfma_f32_16x16x32_bf16(a, b, zacc, 0, 0, 0);
    }

    float s = 0.0f, q = 0.0f;
    const int col = jz + l15;
#pragma unroll
    for (int r = 0; r < 4; ++r) {
        float zv = zacc[r];
        Z[(size_t)(i0 + 4 * kg + r) * 128 + col] = zv;
        s += zv;
        q = fmaf(zv, zv, q);
    }
    s += __shfl_xor(s, 16); s += __shfl_xor(s, 32);
    q += __shfl_xor(q, 16); q += __shfl_xor(q, 32);
    if (kg == 0) {
        ZSP[(size_t)blockIdx.x * 256 + col] = s;
        ZSP[(size_t)blockIdx.x * 256 + 128 + col] = q;
    }
}

// ---------------------------------------------------------------------------
// bn_reduce: BNS[c] = sum_b ZSP[b][c]  (unchanged)
// ---------------------------------------------------------------------------
__global__ void bn_reduce(const float* __restrict__ ZSP, float* __restrict__ BNS)
{
    __shared__ float red[8][32];
    const int tid = threadIdx.x;
    const int c0 = blockIdx.x * 32;
    const int cl = tid & 31, g = tid >> 5;
    float s = 0.0f;
    for (int b = g; b < 512; b += 8)
        s += ZSP[(size_t)b * 256 + c0 + cl];
    red[g][cl] = s;
    __syncthreads();
    if (tid < 32) {
        float t = 0.0f;
#pragma unroll
        for (int g2 = 0; g2 < 8; ++g2) t += red[g2][tid];
        BNS[c0 + tid] = t;
    }
}

// ---------------------------------------------------------------------------
// out = h + relu(z*a+b) @ m2w^T. (unchanged from round 14)
// ---------------------------------------------------------------------------
__global__ void __launch_bounds__(512)
gemm_out_mfma(const float* __restrict__ Z, const float* __restrict__ W,
              const float* __restrict__ BNS,
              const float* __restrict__ bng, const float* __restrict__ bnb,
              float* __restrict__ out)
{
    __shared__ float bnA[128], bnB[128];
    __shared__ ushort_t XS[16][136];
    __shared__ ushort_t WS2[256][40];
    const int tid = threadIdx.x, lane = tid & 63, wid = tid >> 6;
    const int i0 = blockIdx.x * 16;
    const int jw = wid * 32;
    const int l15 = lane & 15, kg = lane >> 4;

    float oprev[2][4];
#pragma unroll
    for (int ni = 0; ni < 2; ++ni)
#pragma unroll
        for (int r = 0; r < 4; ++r)
            oprev[ni][r] = out[(size_t)(i0 + 4 * kg + r) * 256 + jw + 16 * ni + l15];

    if (tid < 128) {
        float s = BNS[tid], q = BNS[128 + tid];
        float mu = s * (1.0f / N_);
        float var = q * (1.0f / N_) - mu * mu;
        float aa = rsqrtf(var + EPSF) * bng[tid];
        bnA[tid] = aa;
        bnB[tid] = bnb[tid] - mu * aa;
    }
    __syncthreads();

    if (tid < 256) {
        int row = tid >> 4, c8 = (tid & 15) * 8;
        const float* zp = Z + (size_t)(i0 + row) * 128 + c8;
        float4 f0 = *(const float4*)zp;
        float4 f1 = *(const float4*)(zp + 4);
        float4 g0, g1;
        g0.x = fmaxf(fmaf(f0.x, bnA[c8 + 0], bnB[c8 + 0]), 0.0f);
        g0.y = fmaxf(fmaf(f0.y, bnA[c8 + 1], bnB[c8 + 1]), 0.0f);
        g0.z = fmaxf(fmaf(f0.z, bnA[c8 + 2], bnB[c8 + 2]), 0.0f);
        g0.w = fmaxf(fmaf(f0.w, bnA[c8 + 3], bnB[c8 + 3]), 0.0f);
        g1.x = fmaxf(fmaf(f1.x, bnA[c8 + 4], bnB[c8 + 4]), 0.0f);
        g1.y = fmaxf(fmaf(f1.y, bnA[c8 + 5], bnB[c8 + 5]), 0.0f);
        g1.z = fmaxf(fmaf(f1.z, bnA[c8 + 6], bnB[c8 + 6]), 0.0f);
        g1.w = fmaxf(fmaf(f1.w, bnA[c8 + 7], bnB[c8 + 7]), 0.0f);
        *(bf16x8*)(&XS[row][c8]) = cvt8(g0, g1);
    }

    f32x4 acc[2];
    acc[0] = 0.0f; acc[1] = 0.0f;

    for (int k0 = 0; k0 < 128; k0 += 32) {
        __syncthreads();
#pragma unroll
        for (int p = 0; p < 2; ++p) {
            int idx = p * 512 + tid;
            int j  = idx >> 2;
            int c8 = (idx & 3) * 8;
            const float* wp = W + (size_t)j * 128 + k0 + c8;
            *(bf16x8*)(&WS2[j][c8]) = cvt8(*(const float4*)wp, *(const float4*)(wp + 4));
        }
        __syncthreads();

        bf16x8 a = *(const bf16x8*)(&XS[l15][k0 + 8 * kg]);
        bf16x8 b[2];
#pragma unroll
        for (int ni = 0; ni < 2; ++ni)
            b[ni] = *(const bf16x8*)(&WS2[jw + 16 * ni + l15][8 * kg]);
#pragma unroll
        for (int ni = 0; ni < 2; ++ni)
            acc[ni] = __builtin_amdgcn_mfma_f32_16x16x32_bf16(a, b[ni], acc[ni], 0, 0, 0);
    }

#pragma unroll
    for (int ni = 0; ni < 2; ++ni)
#pragma unroll
        for (int r = 0; r < 4; ++r) {
            const size_t idx = (size_t)(i0 + 4 * kg + r) * 256
                             + (jw + 16 * ni + l15);
            out[idx] = oprev[ni][r] + acc[ni][r];
        }
}

// ---------------------------------------------------------------------------
extern "C" void kernel_launch(void* const* d_in, const int* in_sizes, int n_in,
                              void* d_out, int out_size, void* d_ws, size_t ws_size,
                              hipStream_t stream)
{
    const float* x    = (const float*)d_in[0];
    const float* wq   = (const float*)d_in[1];
    const float* bq   = (const float*)d_in[2];
    const float* wk   = (const float*)d_in[3];
    const float* bk   = (const float*)d_in[4];
    const float* wv   = (const float*)d_in[5];
    const float* bv   = (const float*)d_in[6];
    const float* cw   = (const float*)d_in[7];
    const float* cb   = (const float*)d_in[8];
    const float* m1w  = (const float*)d_in[9];
    const float* m2w  = (const float*)d_in[10];
    const float* bng  = (const float*)d_in[11];
    const float* bnb  = (const float*)d_in[12];
    const float* ln1g = (const float*)d_in[13];
    const float* ln1b = (const float*)d_in[14];
    const float* ln2g = (const float*)d_in[15];
    const float* ln2b = (const float*)d_in[16];

    float* outF = (float*)d_out;
    char*  wsb  = (char*)d_ws;
    if (ws_size < WS_NEED) return;

    ushort_t* QbG = (ushort_t*)(wsb + OFF_QB);
    ushort_t* KT  = (ushort_t*)(wsb + OFF_KT);
    ushort_t* VT  = (ushort_t*)(wsb + OFF_VT);
    float*    GP  = (float*)(wsb + OFF_GP);
    ushort_t* MTc = (ushort_t*)(wsb + OFF_MT);
    float*    SVP = (float*)(wsb + OFF_SVP);
    float*    SVC = (float*)(wsb + OFF_SVC);
    float*    RED = (float*)(wsb + OFF_RED);
    float*    ZSP = (float*)(wsb + OFF_ZSP);
    float*    BNS = (float*)(wsb + OFF_BNS);
    float*    Z   = (float*)(wsb + OFF_GP);   // GP dead after combine_m

    const dim3 b256(256);
    const dim3 b512(512);

    qkv_mfma<<<dim3(256, 3), b256, 0, stream>>>(x, wq, bq, wk, bk, wv, bv,
                                                QbG, KT, VT, RED, SVP);
    g_mfma<<<dim3(4, 8, 16), b256, 0, stream>>>(KT, VT, GP);
    combine_m<<<256, b256, 0, stream>>>(GP, cw, RED, SVP, cb, MTc, SVC);
    attn_ln_z_mfma<<<512, b512, 0, stream>>>(QbG, MTc, SVC, x,
                                             ln1g, ln1b, ln2g, ln2b, m1w,
                                             outF, Z, ZSP);
    bn_reduce<<<8, b256, 0, stream>>>(ZSP, BNS);
    gemm_out_mfma<<<512, b512, 0, stream>>>(Z, m2w, BNS, bng, bnb, outF);
}

// Round 16
// 94.319 us; speedup vs baseline: 1.3899x; 1.0004x over previous
//
#include <hip/hip_runtime.h>
#include <hip/hip_bf16.h>
#include <math.h>

// ---------------------------------------------------------------------------
// GraphBased_selfAttnLayer — collapsed attention path, 6 launches.
//
//   G_v  = (S_{v-1} K)^T V            (MFMA, K-dim 8192, VT-layout + alignbit)
//   M_u  = scale * sum_v cw[u][v] G_v   -> MTc fragment-coalesced layout
//   attn = sum_u S_{u-1}(Q M_u) + cb*colsum(V); h = x + LN1(attn);
//   l2 = LN2(h) (LDS only); z = l2@m1w^T (fused) ; BN (2-stage) ;
//   out = h + relu(z*a+b) @ m2w^T
//
// Launches: qkv -> g (512 blocks) -> combine -> attn+LN+z -> bn_reduce -> out.
//
// ws (bytes):
//   QbG bf16 [8194][256]   @ 0
//   KT  bf16 [256][8192]   @  4,195,328
//   VT  bf16 [256][8200]   @  8,389,632   (guard cols 0/8193; VT[j][c]=V[c-1][j])
//   GP  f32 [48][256][256] @ 12,588,032   <- after combine: Z f32 [8192][128]
//   MTc bf16 [3][32][256][8] @ 25,170,944
//   SVP f32 [256][256]     @ 25,564,160
//   SVC f32 [256]          @ 25,826,304
//   RED f32 [512]          @ 25,827,328
//   ZSP f32 [512][256]     @ 25,829,376
//   BNS f32 [256]          @ 26,353,664   (ends 26,354,688)
// ---------------------------------------------------------------------------

#define N_ 8192
#define D_ 256
#define H_ 128
#define EPSF 1e-5f

typedef unsigned short ushort_t;
typedef unsigned int uint_t;
typedef __attribute__((ext_vector_type(8))) short bf16x8;
typedef __attribute__((ext_vector_type(4))) short bf16x4;
typedef __attribute__((ext_vector_type(4))) float f32x4;

static const size_t OFF_QB  = 0;
static const size_t OFF_KT  = 4195328;
static const size_t OFF_VT  = 8389632;
static const size_t OFF_GP  = 12588032;
static const size_t OFF_MT  = 25170944;
static const size_t OFF_SVP = 25564160;
static const size_t OFF_SVC = 25826304;
static const size_t OFF_RED = 25827328;
static const size_t OFF_ZSP = 25829376;
static const size_t OFF_BNS = 26353664;
static const size_t WS_NEED = 26354688;

#define VT_S 8200   // VT row stride (elems)

__device__ __forceinline__ ushort_t f2bf(float f) {
    __hip_bfloat16 h = __float2bfloat16(f);
    return reinterpret_cast<ushort_t&>(h);
}

__device__ __forceinline__ bf16x8 cvt8(float4 f0, float4 f1) {
    bf16x8 o;
    o[0] = (short)f2bf(f0.x); o[1] = (short)f2bf(f0.y);
    o[2] = (short)f2bf(f0.z); o[3] = (short)f2bf(f0.w);
    o[4] = (short)f2bf(f1.x); o[5] = (short)f2bf(f1.y);
    o[6] = (short)f2bf(f1.z); o[7] = (short)f2bf(f1.w);
    return o;
}

__device__ __forceinline__ float waveSum(float v)
{
#pragma unroll
    for (int o = 32; o > 0; o >>= 1) v += __shfl_xor(v, o);
    return v;
}

// ---------------------------------------------------------------------------
// qkv via MFMA with LDS-staged operands (proven, unchanged).
// ---------------------------------------------------------------------------
__global__ void __launch_bounds__(256)
qkv_mfma(const float* __restrict__ x,
         const float* __restrict__ wq, const float* __restrict__ bq,
         const float* __restrict__ wk, const float* __restrict__ bk,
         const float* __restrict__ wv, const float* __restrict__ bv,
         ushort_t* __restrict__ QbG, ushort_t* __restrict__ KT,
         ushort_t* __restrict__ VT,
         float* __restrict__ RED, float* __restrict__ SVP)
{
    __shared__ ushort_t XS[32][264];
    __shared__ ushort_t WS[256][40];
    __shared__ float lds4[4];
    const int tid = threadIdx.x, lane = tid & 63, wid = tid >> 6;
    const int sel = blockIdx.y;
    const int i0 = blockIdx.x * 32;
    const int jw = wid * 64;
    const int l15 = lane & 15, kg = lane >> 4;
    const float* W = (sel == 0) ? wq : ((sel == 1) ? wk : wv);
    const float* B = (sel == 0) ? bq : ((sel == 1) ? bk : bv);

    if (sel == 0 && blockIdx.x == 0) {
        QbG[tid] = 0; QbG[(size_t)8193 * 256 + tid] = 0;
        VT[(size_t)tid * VT_S] = 0; VT[(size_t)tid * VT_S + 8193] = 0;
    }

#pragma unroll
    for (int p = 0; p < 4; ++p) {
        int lin = p * 256 + tid;
        int row = lin >> 5;
        int c8  = (lin & 31) * 8;
        const float* xp = x + (size_t)(i0 + row) * 256 + c8;
        *(bf16x8*)(&XS[row][c8]) = cvt8(*(const float4*)xp, *(const float4*)(xp + 4));
    }

    f32x4 acc[2][4];
#pragma unroll
    for (int mi = 0; mi < 2; ++mi)
#pragma unroll
        for (int ni = 0; ni < 4; ++ni) acc[mi][ni] = 0.0f;

    for (int k0 = 0; k0 < 256; k0 += 32) {
        __syncthreads();
#pragma unroll
        for (int p = 0; p < 4; ++p) {
            int j  = p * 64 + (tid >> 2);
            int c8 = (tid & 3) * 8;
            const float* wp = W + (size_t)j * 256 + k0 + c8;
            *(bf16x8*)(&WS[j][c8]) = cvt8(*(const float4*)wp, *(const float4*)(wp + 4));
        }
        __syncthreads();

        bf16x8 a[2], b[4];
#pragma unroll
        for (int mi = 0; mi < 2; ++mi)
            a[mi] = *(const bf16x8*)(&XS[16 * mi + l15][k0 + 8 * kg]);
#pragma unroll
        for (int ni = 0; ni < 4; ++ni)
            b[ni] = *(const bf16x8*)(&WS[jw + 16 * ni + l15][8 * kg]);
#pragma unroll
        for (int mi = 0; mi < 2; ++mi)
#pragma unroll
            for (int ni = 0; ni < 4; ++ni)
                acc[mi][ni] = __builtin_amdgcn_mfma_f32_16x16x32_bf16(a[mi], b[ni], acc[mi][ni], 0, 0, 0);
    }

    float ssq = 0.0f;
    float colp[4] = {0.0f, 0.0f, 0.0f, 0.0f};

    if (sel == 0) {
#pragma unroll
        for (int mi = 0; mi < 2; ++mi)
#pragma unroll
            for (int ni = 0; ni < 4; ++ni) {
                const int col = jw + 16 * ni + l15;
                const float bias = B[col];
#pragma unroll
                for (int r = 0; r < 4; ++r) {
                    const int row = i0 + 16 * mi + 4 * kg + r;
                    float val = acc[mi][ni][r] + bias;
                    QbG[(size_t)(row + 1) * 256 + col] = f2bf(val);
                    ssq = fmaf(val, val, ssq);
                }
            }
    } else if (sel == 1) {
#pragma unroll
        for (int mi = 0; mi < 2; ++mi)
#pragma unroll
            for (int ni = 0; ni < 4; ++ni) {
                const int col = jw + 16 * ni + l15;   // d
                const float bias = B[col];
                const int tb = i0 + 16 * mi + 4 * kg;
                bf16x4 pk;
#pragma unroll
                for (int r = 0; r < 4; ++r) {
                    float val = acc[mi][ni][r] + bias;
                    ssq = fmaf(val, val, ssq);
                    pk[r] = (short)f2bf(val);
                }
                *(bf16x4*)(KT + (size_t)col * 8192 + tb) = pk;
            }
    } else {
#pragma unroll
        for (int mi = 0; mi < 2; ++mi)
#pragma unroll
            for (int ni = 0; ni < 4; ++ni) {
                const int col = jw + 16 * ni + l15;   // j
                const float bias = B[col];
                const int tb = i0 + 16 * mi + 4 * kg;
                float v0 = acc[mi][ni][0] + bias, v1 = acc[mi][ni][1] + bias;
                float v2 = acc[mi][ni][2] + bias, v3 = acc[mi][ni][3] + bias;
                colp[ni] += v0 + v1 + v2 + v3;
                ushort_t* p = VT + (size_t)col * VT_S + tb + 1;
                p[0] = f2bf(v0);
                *(uint_t*)(p + 1) = (uint_t)f2bf(v1) | ((uint_t)f2bf(v2) << 16);
                p[3] = f2bf(v3);
            }
    }

    if (sel < 2) {
        float s = ssq;
#pragma unroll
        for (int o = 32; o > 0; o >>= 1) s += __shfl_down(s, o);
        if (lane == 0) lds4[wid] = s;
        __syncthreads();
        if (tid == 0)
            RED[sel * 256 + blockIdx.x] = lds4[0] + lds4[1] + lds4[2] + lds4[3];
    } else {
#pragma unroll
        for (int ni = 0; ni < 4; ++ni) {
            float v = colp[ni];
            v += __shfl_xor(v, 16);
            v += __shfl_xor(v, 32);
            if (kg == 0)
                SVP[(size_t)blockIdx.x * 256 + jw + 16 * ni + l15] = v;
        }
    }
}

// ---------------------------------------------------------------------------
// G_v[d][j] = sum_t K[t][d] * V[t+1-v][j].  grid (4, 8, 16) = 512 blocks.
// Block: 64d x 32j; 4 waves: (wid>>1)=d-half (2 mi), (wid&1)=j-half (16 j).
// 2 blocks/CU for latency hiding; A-redundancy 4x -> 2x; regs halved.
// ---------------------------------------------------------------------------
__global__ void __launch_bounds__(256)
g_mfma(const ushort_t* __restrict__ KT, const ushort_t* __restrict__ VT,
       float* __restrict__ GP)
{
    const int tid = threadIdx.x, lane = tid & 63, wid = tid >> 6;
    const int d0 = blockIdx.x * 64 + (wid >> 1) * 32;
    const int jw = blockIdx.y * 32 + (wid & 1) * 16;
    const int ks = blockIdx.z;
    const int l15 = lane & 15, kg = lane >> 4;

    f32x4 acc[3][2];
#pragma unroll
    for (int v = 0; v < 3; ++v) { acc[v][0] = 0.0f; acc[v][1] = 0.0f; }

    for (int tt = 0; tt < 512; tt += 32) {
        const int t0 = ks * 512 + tt;
        bf16x8 a[2];
#pragma unroll
        for (int mi = 0; mi < 2; ++mi)
            a[mi] = *(const bf16x8*)(KT + (size_t)(d0 + 16 * mi + l15) * 8192 + t0 + 8 * kg);

        const ushort_t* vp = VT + (size_t)(jw + l15) * VT_S + t0 + 8 * kg;
        uint4 r0 = *(const uint4*)vp;          // cols +0..7 -> v=2
        uint4 r2 = *(const uint4*)(vp + 2);    // cols +2..9 -> v=0
        uint4 m1;
        m1.x = (r0.x >> 16) | (r2.x << 16);
        m1.y = (r0.y >> 16) | (r2.y << 16);
        m1.z = (r0.z >> 16) | (r2.z << 16);
        m1.w = (r0.w >> 16) | (r2.w << 16);    // cols +1..8 -> v=1
        bf16x8 b2 = __builtin_bit_cast(bf16x8, r0);
        bf16x8 b0 = __builtin_bit_cast(bf16x8, r2);
        bf16x8 b1 = __builtin_bit_cast(bf16x8, m1);
#pragma unroll
        for (int mi = 0; mi < 2; ++mi) {
            acc[0][mi] = __builtin_amdgcn_mfma_f32_16x16x32_bf16(a[mi], b0, acc[0][mi], 0, 0, 0);
            acc[1][mi] = __builtin_amdgcn_mfma_f32_16x16x32_bf16(a[mi], b1, acc[1][mi], 0, 0, 0);
            acc[2][mi] = __builtin_amdgcn_mfma_f32_16x16x32_bf16(a[mi], b2, acc[2][mi], 0, 0, 0);
        }
    }

#pragma unroll
    for (int v = 0; v < 3; ++v) {
        float* gp = GP + (size_t)(ks * 3 + v) * 65536;
#pragma unroll
        for (int mi = 0; mi < 2; ++mi)
#pragma unroll
            for (int r = 0; r < 4; ++r)
                gp[(size_t)(d0 + 16 * mi + 4 * kg + r) * 256 + (jw + l15)]
                    = acc[v][mi][r];
    }
}

// ---------------------------------------------------------------------------
// MTc[u][kb][j][e] = scale * sum_v cw[u][v] * sum_ks GP[ks*3+v][d=kb*8+e][j].
// (unchanged)
// ---------------------------------------------------------------------------
__global__ void combine_m(const float* __restrict__ GP, const float* __restrict__ cw,
                          const float* __restrict__ RED, const float* __restrict__ SVP,
                          const float* __restrict__ cb,
                          ushort_t* __restrict__ MTc, float* __restrict__ SVC)
{
    __shared__ float lds8[8];
    __shared__ float scsh;
    const int d = blockIdx.x, j = threadIdx.x;

    float sq = RED[j], sk = RED[256 + j];
#pragma unroll
    for (int o = 32; o > 0; o >>= 1) { sq += __shfl_down(sq, o); sk += __shfl_down(sk, o); }
    if ((j & 63) == 0) { lds8[j >> 6] = sq; lds8[4 + (j >> 6)] = sk; }

    float g[3] = {0.0f, 0.0f, 0.0f};
    for (int ks = 0; ks < 16; ++ks)
#pragma unroll
        for (int v = 0; v < 3; ++v)
            g[v] += GP[(size_t)(ks * 3 + v) * 65536 + (size_t)d * 256 + j];

    __syncthreads();
    if (j == 0) {
        float SQ = lds8[0] + lds8[1] + lds8[2] + lds8[3];
        float SK = lds8[4] + lds8[5] + lds8[6] + lds8[7];
        scsh = rsqrtf(SQ) * rsqrtf(SK);
    }
    __syncthreads();
    const float sc = scsh;

#pragma unroll
    for (int u = 0; u < 3; ++u) {
        float m = sc * (cw[u * 3 + 0] * g[0] + cw[u * 3 + 1] * g[1] + cw[u * 3 + 2] * g[2]);
        MTc[(size_t)u * 65536 + (size_t)(d >> 3) * 2048 + (size_t)j * 8 + (d & 7)]
            = f2bf(m);
    }
    if (d == 0) {
        float s = 0.0f;
        for (int b = 0; b < 256; ++b) s += SVP[(size_t)b * 256 + j];
        SVC[j] = cb[0] * s;
    }
}

// ---------------------------------------------------------------------------
// attn + LN + z fused. 512 threads (8 waves), 16 rows/block, grid 512.
// (unchanged from round 14)
// ---------------------------------------------------------------------------
__global__ void __launch_bounds__(512)
attn_ln_z_mfma(const ushort_t* __restrict__ QbG, const ushort_t* __restrict__ MTc,
               const float* __restrict__ SVC, const float* __restrict__ x,
               const float* __restrict__ ln1g, const float* __restrict__ ln1b,
               const float* __restrict__ ln2g, const float* __restrict__ ln2b,
               const float* __restrict__ m1w,
               float* __restrict__ h, float* __restrict__ Z,
               float* __restrict__ ZSP)
{
    __shared__ ushort_t QS[18][264];
    __shared__ float OUT[16][260];
    __shared__ ushort_t WS[128][40];
    const int tid = threadIdx.x, lane = tid & 63, wid = tid >> 6;  // wid 0..7
    const int i0 = blockIdx.x * 16;
    const int jw = wid * 32;
    const int l15 = lane & 15, kg = lane >> 4;

    float4 xpre0 = *(const float4*)(x + (size_t)(i0 + wid * 2 + 0) * 256 + lane * 4);
    float4 xpre1 = *(const float4*)(x + (size_t)(i0 + wid * 2 + 1) * 256 + lane * 4);

    {
        int row = tid >> 5, c8 = (tid & 31) * 8;
        *(bf16x8*)(&QS[row][c8]) = *(const bf16x8*)(QbG + (size_t)(i0 + row) * 256 + c8);
        int idx = tid + 512;
        if (idx < 576) {
            row = idx >> 5; c8 = (idx & 31) * 8;
            *(bf16x8*)(&QS[row][c8]) = *(const bf16x8*)(QbG + (size_t)(i0 + row) * 256 + c8);
        }
    }
    __syncthreads();

    f32x4 acc[2];
    acc[0] = 0.0f; acc[1] = 0.0f;

    for (int k0 = 0; k0 < 256; k0 += 32) {
        bf16x8 a[3], b[3][2];
#pragma unroll
        for (int u = 0; u < 3; ++u)
            a[u] = *(const bf16x8*)(&QS[l15 + u][k0 + 8 * kg]);
#pragma unroll
        for (int u = 0; u < 3; ++u)
#pragma unroll
            for (int ni = 0; ni < 2; ++ni)
                b[u][ni] = *(const bf16x8*)(MTc + (size_t)u * 65536
                    + (size_t)((k0 >> 3) + kg) * 2048
                    + (size_t)(jw + 16 * ni + l15) * 8);
#pragma unroll
        for (int ni = 0; ni < 2; ++ni)
#pragma unroll
            for (int u = 0; u < 3; ++u)
                acc[ni] = __builtin_amdgcn_mfma_f32_16x16x32_bf16(
                    a[u], b[u][ni], acc[ni], 0, 0, 0);
    }

#pragma unroll
    for (int ni = 0; ni < 2; ++ni) {
        const int col = jw + 16 * ni + l15;
        const float sv = SVC[col];
#pragma unroll
        for (int r = 0; r < 4; ++r)
            OUT[4 * kg + r][col] = acc[ni][r] + sv;
    }
    __syncthreads();

    const float4 g14 = *(const float4*)(ln1g + lane * 4);
    const float4 b14 = *(const float4*)(ln1b + lane * 4);
    const float4 g24 = *(const float4*)(ln2g + lane * 4);
    const float4 b24 = *(const float4*)(ln2b + lane * 4);
#pragma unroll
    for (int rr = 0; rr < 2; ++rr) {
        const int row_l = wid * 2 + rr;
        const size_t off = (size_t)(i0 + row_l) * 256 + lane * 4;

        float4 a4 = *(const float4*)&OUT[row_l][lane * 4];
        float m = waveSum(a4.x + a4.y + a4.z + a4.w) * (1.0f / D_);
        float4 d4 = make_float4(a4.x - m, a4.y - m, a4.z - m, a4.w - m);
        float var = waveSum(d4.x * d4.x + d4.y * d4.y + d4.z * d4.z + d4.w * d4.w) * (1.0f / D_);
        float rs = rsqrtf(var + EPSF);

        float4 x4 = (rr == 0) ? xpre0 : xpre1;
        float4 h4;
        h4.x = x4.x + d4.x * rs * g14.x + b14.x;
        h4.y = x4.y + d4.y * rs * g14.y + b14.y;
        h4.z = x4.z + d4.z * rs * g14.z + b14.z;
        h4.w = x4.w + d4.w * rs * g14.w + b14.w;
        *(float4*)(h + off) = h4;

        float m2 = waveSum(h4.x + h4.y + h4.z + h4.w) * (1.0f / D_);
        float4 e4 = make_float4(h4.x - m2, h4.y - m2, h4.z - m2, h4.w - m2);
        float v2 = waveSum(e4.x * e4.x + e4.y * e4.y + e4.z * e4.z + e4.w * e4.w) * (1.0f / D_);
        float rs2 = rsqrtf(v2 + EPSF);

        float4 o4;
        o4.x = e4.x * rs2 * g24.x + b24.x;
        o4.y = e4.y * rs2 * g24.y + b24.y;
        o4.z = e4.z * rs2 * g24.z + b24.z;
        o4.w = e4.w * rs2 * g24.w + b24.w;
        *(float4*)&OUT[row_l][lane * 4] = o4;
    }
    __syncthreads();

    const int jz = wid * 16;
    f32x4 zacc;
    zacc = 0.0f;

    for (int k0 = 0; k0 < 256; k0 += 32) {
        if (k0) __syncthreads();
        {
            int j  = tid >> 2;
            int c8 = (tid & 3) * 8;
            const float* wp = m1w + (size_t)j * 256 + k0 + c8;
            *(bf16x8*)(&WS[j][c8]) = cvt8(*(const float4*)wp, *(const float4*)(wp + 4));
        }
        __syncthreads();

        bf16x8 a, b;
        {
            const float* lp = &OUT[l15][k0 + 8 * kg];
            a = cvt8(*(const float4*)lp, *(const float4*)(lp + 4));
        }
        b = *(const bf16x8*)(&WS[jz + l15][8 * kg]);
        zacc = __builtin_amdgcn_mfma_f32_16x16x32_bf16(a, b, zacc, 0, 0, 0);
    }

    float s = 0.0f, q = 0.0f;
    const int col = jz + l15;
#pragma unroll
    for (int r = 0; r < 4; ++r) {
        float zv = zacc[r];
        Z[(size_t)(i0 + 4 * kg + r) * 128 + col] = zv;
        s += zv;
        q = fmaf(zv, zv, q);
    }
    s += __shfl_xor(s, 16); s += __shfl_xor(s, 32);
    q += __shfl_xor(q, 16); q += __shfl_xor(q, 32);
    if (kg == 0) {
        ZSP[(size_t)blockIdx.x * 256 + col] = s;
        ZSP[(size_t)blockIdx.x * 256 + 128 + col] = q;
    }
}

// ---------------------------------------------------------------------------
// bn_reduce: BNS[c] = sum_b ZSP[b][c]  (unchanged)
// ---------------------------------------------------------------------------
__global__ void bn_reduce(const float* __restrict__ ZSP, float* __restrict__ BNS)
{
    __shared__ float red[8][32];
    const int tid = threadIdx.x;
    const int c0 = blockIdx.x * 32;
    const int cl = tid & 31, g = tid >> 5;
    float s = 0.0f;
    for (int b = g; b < 512; b += 8)
        s += ZSP[(size_t)b * 256 + c0 + cl];
    red[g][cl] = s;
    __syncthreads();
    if (tid < 32) {
        float t = 0.0f;
#pragma unroll
        for (int g2 = 0; g2 < 8; ++g2) t += red[g2][tid];
        BNS[c0 + tid] = t;
    }
}

// ---------------------------------------------------------------------------
// out = h + relu(z*a+b) @ m2w^T. (unchanged from round 14)
// ---------------------------------------------------------------------------
__global__ void __launch_bounds__(512)
gemm_out_mfma(const float* __restrict__ Z, const float* __restrict__ W,
              const float* __restrict__ BNS,
              const float* __restrict__ bng, const float* __restrict__ bnb,
              float* __restrict__ out)
{
    __shared__ float bnA[128], bnB[128];
    __shared__ ushort_t XS[16][136];
    __shared__ ushort_t WS2[256][40];
    const int tid = threadIdx.x, lane = tid & 63, wid = tid >> 6;
    const int i0 = blockIdx.x * 16;
    const int jw = wid * 32;
    const int l15 = lane & 15, kg = lane >> 4;

    float oprev[2][4];
#pragma unroll
    for (int ni = 0; ni < 2; ++ni)
#pragma unroll
        for (int r = 0; r < 4; ++r)
            oprev[ni][r] = out[(size_t)(i0 + 4 * kg + r) * 256 + jw + 16 * ni + l15];

    if (tid < 128) {
        float s = BNS[tid], q = BNS[128 + tid];
        float mu = s * (1.0f / N_);
        float var = q * (1.0f / N_) - mu * mu;
        float aa = rsqrtf(var + EPSF) * bng[tid];
        bnA[tid] = aa;
        bnB[tid] = bnb[tid] - mu * aa;
    }
    __syncthreads();

    if (tid < 256) {
        int row = tid >> 4, c8 = (tid & 15) * 8;
        const float* zp = Z + (size_t)(i0 + row) * 128 + c8;
        float4 f0 = *(const float4*)zp;
        float4 f1 = *(const float4*)(zp + 4);
        float4 g0, g1;
        g0.x = fmaxf(fmaf(f0.x, bnA[c8 + 0], bnB[c8 + 0]), 0.0f);
        g0.y = fmaxf(fmaf(f0.y, bnA[c8 + 1], bnB[c8 + 1]), 0.0f);
        g0.z = fmaxf(fmaf(f0.z, bnA[c8 + 2], bnB[c8 + 2]), 0.0f);
        g0.w = fmaxf(fmaf(f0.w, bnA[c8 + 3], bnB[c8 + 3]), 0.0f);
        g1.x = fmaxf(fmaf(f1.x, bnA[c8 + 4], bnB[c8 + 4]), 0.0f);
        g1.y = fmaxf(fmaf(f1.y, bnA[c8 + 5], bnB[c8 + 5]), 0.0f);
        g1.z = fmaxf(fmaf(f1.z, bnA[c8 + 6], bnB[c8 + 6]), 0.0f);
        g1.w = fmaxf(fmaf(f1.w, bnA[c8 + 7], bnB[c8 + 7]), 0.0f);
        *(bf16x8*)(&XS[row][c8]) = cvt8(g0, g1);
    }

    f32x4 acc[2];
    acc[0] = 0.0f; acc[1] = 0.0f;

    for (int k0 = 0; k0 < 128; k0 += 32) {
        __syncthreads();
#pragma unroll
        for (int p = 0; p < 2; ++p) {
            int idx = p * 512 + tid;
            int j  = idx >> 2;
            int c8 = (idx & 3) * 8;
            const float* wp = W + (size_t)j * 128 + k0 + c8;
            *(bf16x8*)(&WS2[j][c8]) = cvt8(*(const float4*)wp, *(const float4*)(wp + 4));
        }
        __syncthreads();

        bf16x8 a = *(const bf16x8*)(&XS[l15][k0 + 8 * kg]);
        bf16x8 b[2];
#pragma unroll
        for (int ni = 0; ni < 2; ++ni)
            b[ni] = *(const bf16x8*)(&WS2[jw + 16 * ni + l15][8 * kg]);
#pragma unroll
        for (int ni = 0; ni < 2; ++ni)
            acc[ni] = __builtin_amdgcn_mfma_f32_16x16x32_bf16(a, b[ni], acc[ni], 0, 0, 0);
    }

#pragma unroll
    for (int ni = 0; ni < 2; ++ni)
#pragma unroll
        for (int r = 0; r < 4; ++r) {
            const size_t idx = (size_t)(i0 + 4 * kg + r) * 256
                             + (jw + 16 * ni + l15);
            out[idx] = oprev[ni][r] + acc[ni][r];
        }
}

// ---------------------------------------------------------------------------
extern "C" void kernel_launch(void* const* d_in, const int* in_sizes, int n_in,
                              void* d_out, int out_size, void* d_ws, size_t ws_size,
                              hipStream_t stream)
{
    const float* x    = (const float*)d_in[0];
    const float* wq   = (const float*)d_in[1];
    const float* bq   = (const float*)d_in[2];
    const float* wk   = (const float*)d_in[3];
    const float* bk   = (const float*)d_in[4];
    const float* wv   = (const float*)d_in[5];
    const float* bv   = (const float*)d_in[6];
    const float* cw   = (const float*)d_in[7];
    const float* cb   = (const float*)d_in[8];
    const float* m1w  = (const float*)d_in[9];
    const float* m2w  = (const float*)d_in[10];
    const float* bng  = (const float*)d_in[11];
    const float* bnb  = (const float*)d_in[12];
    const float* ln1g = (const float*)d_in[13];
    const float* ln1b = (const float*)d_in[14];
    const float* ln2g = (const float*)d_in[15];
    const float* ln2b = (const float*)d_in[16];

    float* outF = (float*)d_out;
    char*  wsb  = (char*)d_ws;
    if (ws_size < WS_NEED) return;

    ushort_t* QbG = (ushort_t*)(wsb + OFF_QB);
    ushort_t* KT  = (ushort_t*)(wsb + OFF_KT);
    ushort_t* VT  = (ushort_t*)(wsb + OFF_VT);
    float*    GP  = (float*)(wsb + OFF_GP);
    ushort_t* MTc = (ushort_t*)(wsb + OFF_MT);
    float*    SVP = (float*)(wsb + OFF_SVP);
    float*    SVC = (float*)(wsb + OFF_SVC);
    float*    RED = (float*)(wsb + OFF_RED);
    float*    ZSP = (float*)(wsb + OFF_ZSP);
    float*    BNS = (float*)(wsb + OFF_BNS);
    float*    Z   = (float*)(wsb + OFF_GP);   // GP dead after combine_m

    const dim3 b256(256);
    const dim3 b512(512);

    qkv_mfma<<<dim3(256, 3), b256, 0, stream>>>(x, wq, bq, wk, bk, wv, bv,
                                                QbG, KT, VT, RED, SVP);
    g_mfma<<<dim3(4, 8, 16), b256, 0, stream>>>(KT, VT, GP);
    combine_m<<<256, b256, 0, stream>>>(GP, cw, RED, SVP, cb, MTc, SVC);
    attn_ln_z_mfma<<<512, b512, 0, stream>>>(QbG, MTc, SVC, x,
                                             ln1g, ln1b, ln2g, ln2b, m1w,
                                             outF, Z, ZSP);
    bn_reduce<<<8, b256, 0, stream>>>(ZSP, BNS);
    gemm_out_mfma<<<512, b512, 0, stream>>>(Z, m2w, BNS, bng, bnb, outF);
}

// Round 17
// 88.565 us; speedup vs baseline: 1.4802x; 1.0650x over previous
//
#include <hip/hip_runtime.h>
#include <hip/hip_bf16.h>
#include <math.h>

// ---------------------------------------------------------------------------
// GraphBased_selfAttnLayer — collapsed attention path, 7 launches.
//
//   G_v  = (S_{v-1} K)^T V            (MFMA, K-dim 8192, VT-layout + alignbit)
//   M_u  = scale * sum_v cw[u][v] G_v   -> MTc fragment-coalesced layout
//   attn = sum_u S_{u-1}(Q M_u) + cb*colsum(V); h = x + LN1(attn);
//   l2 = LN2(h) (LDS only); z = l2@m1w^T (fused) ; BN (2-stage) ;
//   out = h + relu(z*a+b) @ m2w^T
//
// Launches: prep_w -> qkv -> g -> combine -> attn+LN+z -> bn_reduce -> out.
// ALL weight B-operands in fragment-coalesced bf16 layouts (WC/M1C/M2C/MTc)
// -> direct coalesced loads, no LDS staging, no K-loop barriers.
//
// Coalesced layout: C[kb][j][e] = W[j][k=kb*8+e]; frag load for MFMA B is
// 16 consecutive 16B chunks per 16-lane group.
//
// ws (bytes):
//   QbG bf16 [8194][256]   @ 0
//   KT  bf16 [256][8192]   @  4,195,328
//   VT  bf16 [256][8200]   @  8,389,632   (guard cols 0/8193; VT[j][c]=V[c-1][j])
//   GP  f32 [48][256][256] @ 12,588,032   <- after combine: Z f32 [8192][128]
//   MTc bf16 [3][32][256][8] @ 25,170,944
//   SVP f32 [256][256]     @ 25,564,160
//   SVC f32 [256]          @ 25,826,304
//   RED f32 [512]          @ 25,827,328
//   ZSP f32 [512][256]     @ 25,829,376
//   BNS f32 [256]          @ 26,353,664
//   WC  bf16 [3][32][256][8] @ 26,354,688
//   M1C bf16 [32][128][8]  @ 26,747,904
//   M2C bf16 [16][256][8]  @ 26,813,440   (ends 26,878,976)
// ---------------------------------------------------------------------------

#define N_ 8192
#define D_ 256
#define H_ 128
#define EPSF 1e-5f

typedef unsigned short ushort_t;
typedef unsigned int uint_t;
typedef __attribute__((ext_vector_type(8))) short bf16x8;
typedef __attribute__((ext_vector_type(4))) short bf16x4;
typedef __attribute__((ext_vector_type(4))) float f32x4;

static const size_t OFF_QB  = 0;
static const size_t OFF_KT  = 4195328;
static const size_t OFF_VT  = 8389632;
static const size_t OFF_GP  = 12588032;
static const size_t OFF_MT  = 25170944;
static const size_t OFF_SVP = 25564160;
static const size_t OFF_SVC = 25826304;
static const size_t OFF_RED = 25827328;
static const size_t OFF_ZSP = 25829376;
static const size_t OFF_BNS = 26353664;
static const size_t OFF_WC  = 26354688;
static const size_t OFF_M1C = 26747904;
static const size_t OFF_M2C = 26813440;
static const size_t WS_NEED = 26878976;

#define VT_S 8200   // VT row stride (elems)

__device__ __forceinline__ ushort_t f2bf(float f) {
    __hip_bfloat16 h = __float2bfloat16(f);
    return reinterpret_cast<ushort_t&>(h);
}

__device__ __forceinline__ bf16x8 cvt8(float4 f0, float4 f1) {
    bf16x8 o;
    o[0] = (short)f2bf(f0.x); o[1] = (short)f2bf(f0.y);
    o[2] = (short)f2bf(f0.z); o[3] = (short)f2bf(f0.w);
    o[4] = (short)f2bf(f1.x); o[5] = (short)f2bf(f1.y);
    o[6] = (short)f2bf(f1.z); o[7] = (short)f2bf(f1.w);
    return o;
}

__device__ __forceinline__ float waveSum(float v)
{
#pragma unroll
    for (int o = 32; o > 0; o >>= 1) v += __shfl_xor(v, o);
    return v;
}

// ---------------------------------------------------------------------------
// prep_w: convert wq/wk/wv -> WC, m1w -> M1C, m2w -> M2C (coalesced bf16);
// zero QbG/VT guards. grid 145 x 256.
// ---------------------------------------------------------------------------
__global__ void prep_w(const float* __restrict__ wq, const float* __restrict__ wk,
                       const float* __restrict__ wv, const float* __restrict__ m1w,
                       const float* __restrict__ m2w,
                       ushort_t* __restrict__ WC, ushort_t* __restrict__ M1C,
                       ushort_t* __restrict__ M2C,
                       ushort_t* __restrict__ QbG, ushort_t* __restrict__ VT)
{
    const int bid = blockIdx.x, tid = threadIdx.x;
    if (bid < 96) {
        const int sel = bid >> 5, kb = bid & 31;
        const float* W = (sel == 0) ? wq : ((sel == 1) ? wk : wv);
        const float* p = W + (size_t)tid * 256 + kb * 8;
        *(bf16x8*)(WC + (size_t)sel * 65536 + (size_t)kb * 2048 + (size_t)tid * 8)
            = cvt8(*(const float4*)p, *(const float4*)(p + 4));
    } else if (bid < 128) {
        const int kb = bid - 96;
        if (tid < 128) {
            const float* p = m1w + (size_t)tid * 256 + kb * 8;
            *(bf16x8*)(M1C + (size_t)kb * 1024 + (size_t)tid * 8)
                = cvt8(*(const float4*)p, *(const float4*)(p + 4));
        }
    } else if (bid < 144) {
        const int kb = bid - 128;
        const float* p = m2w + (size_t)tid * 128 + kb * 8;
        *(bf16x8*)(M2C + (size_t)kb * 2048 + (size_t)tid * 8)
            = cvt8(*(const float4*)p, *(const float4*)(p + 4));
    } else {
        QbG[tid] = 0; QbG[(size_t)8193 * 256 + tid] = 0;
        VT[(size_t)tid * VT_S] = 0; VT[(size_t)tid * VT_S + 8193] = 0;
    }
}

// ---------------------------------------------------------------------------
// qkv via MFMA: A (x tile) LDS-staged once; B direct-coalesced from WC.
// grid (256, 3), 256 thr. No K-loop barriers.
// ---------------------------------------------------------------------------
__global__ void __launch_bounds__(256)
qkv_mfma(const float* __restrict__ x, const ushort_t* __restrict__ WC,
         const float* __restrict__ bq, const float* __restrict__ bk,
         const float* __restrict__ bv,
         ushort_t* __restrict__ QbG, ushort_t* __restrict__ KT,
         ushort_t* __restrict__ VT,
         float* __restrict__ RED, float* __restrict__ SVP)
{
    __shared__ ushort_t XS[32][264];
    __shared__ float lds4[4];
    const int tid = threadIdx.x, lane = tid & 63, wid = tid >> 6;
    const int sel = blockIdx.y;
    const int i0 = blockIdx.x * 32;
    const int jw = wid * 64;
    const int l15 = lane & 15, kg = lane >> 4;
    const ushort_t* Wc = WC + (size_t)sel * 65536;
    const float* B = (sel == 0) ? bq : ((sel == 1) ? bk : bv);

#pragma unroll
    for (int p = 0; p < 4; ++p) {
        int lin = p * 256 + tid;
        int row = lin >> 5;
        int c8  = (lin & 31) * 8;
        const float* xp = x + (size_t)(i0 + row) * 256 + c8;
        *(bf16x8*)(&XS[row][c8]) = cvt8(*(const float4*)xp, *(const float4*)(xp + 4));
    }
    __syncthreads();

    f32x4 acc[2][4];
#pragma unroll
    for (int mi = 0; mi < 2; ++mi)
#pragma unroll
        for (int ni = 0; ni < 4; ++ni) acc[mi][ni] = 0.0f;

    for (int k0 = 0; k0 < 256; k0 += 32) {
        bf16x8 a[2], b[4];
#pragma unroll
        for (int mi = 0; mi < 2; ++mi)
            a[mi] = *(const bf16x8*)(&XS[16 * mi + l15][k0 + 8 * kg]);
#pragma unroll
        for (int ni = 0; ni < 4; ++ni)
            b[ni] = *(const bf16x8*)(Wc + (size_t)((k0 >> 3) + kg) * 2048
                                        + (size_t)(jw + 16 * ni + l15) * 8);
#pragma unroll
        for (int mi = 0; mi < 2; ++mi)
#pragma unroll
            for (int ni = 0; ni < 4; ++ni)
                acc[mi][ni] = __builtin_amdgcn_mfma_f32_16x16x32_bf16(a[mi], b[ni], acc[mi][ni], 0, 0, 0);
    }

    float ssq = 0.0f;
    float colp[4] = {0.0f, 0.0f, 0.0f, 0.0f};

    if (sel == 0) {
#pragma unroll
        for (int mi = 0; mi < 2; ++mi)
#pragma unroll
            for (int ni = 0; ni < 4; ++ni) {
                const int col = jw + 16 * ni + l15;
                const float bias = B[col];
#pragma unroll
                for (int r = 0; r < 4; ++r) {
                    const int row = i0 + 16 * mi + 4 * kg + r;
                    float val = acc[mi][ni][r] + bias;
                    QbG[(size_t)(row + 1) * 256 + col] = f2bf(val);
                    ssq = fmaf(val, val, ssq);
                }
            }
    } else if (sel == 1) {
#pragma unroll
        for (int mi = 0; mi < 2; ++mi)
#pragma unroll
            for (int ni = 0; ni < 4; ++ni) {
                const int col = jw + 16 * ni + l15;   // d
                const float bias = B[col];
                const int tb = i0 + 16 * mi + 4 * kg;
                bf16x4 pk;
#pragma unroll
                for (int r = 0; r < 4; ++r) {
                    float val = acc[mi][ni][r] + bias;
                    ssq = fmaf(val, val, ssq);
                    pk[r] = (short)f2bf(val);
                }
                *(bf16x4*)(KT + (size_t)col * 8192 + tb) = pk;
            }
    } else {
#pragma unroll
        for (int mi = 0; mi < 2; ++mi)
#pragma unroll
            for (int ni = 0; ni < 4; ++ni) {
                const int col = jw + 16 * ni + l15;   // j
                const float bias = B[col];
                const int tb = i0 + 16 * mi + 4 * kg;
                float v0 = acc[mi][ni][0] + bias, v1 = acc[mi][ni][1] + bias;
                float v2 = acc[mi][ni][2] + bias, v3 = acc[mi][ni][3] + bias;
                colp[ni] += v0 + v1 + v2 + v3;
                ushort_t* p = VT + (size_t)col * VT_S + tb + 1;
                p[0] = f2bf(v0);
                *(uint_t*)(p + 1) = (uint_t)f2bf(v1) | ((uint_t)f2bf(v2) << 16);
                p[3] = f2bf(v3);
            }
    }

    if (sel < 2) {
        float s = ssq;
#pragma unroll
        for (int o = 32; o > 0; o >>= 1) s += __shfl_down(s, o);
        if (lane == 0) lds4[wid] = s;
        __syncthreads();
        if (tid == 0)
            RED[sel * 256 + blockIdx.x] = lds4[0] + lds4[1] + lds4[2] + lds4[3];
    } else {
#pragma unroll
        for (int ni = 0; ni < 4; ++ni) {
            float v = colp[ni];
            v += __shfl_xor(v, 16);
            v += __shfl_xor(v, 32);
            if (kg == 0)
                SVP[(size_t)blockIdx.x * 256 + jw + 16 * ni + l15] = v;
        }
    }
}

// ---------------------------------------------------------------------------
// G_v[d][j] = sum_t K[t][d] * V[t+1-v][j].  grid (4, 8, 16) = 512 blocks.
// (unchanged from round 16)
// ---------------------------------------------------------------------------
__global__ void __launch_bounds__(256)
g_mfma(const ushort_t* __restrict__ KT, const ushort_t* __restrict__ VT,
       float* __restrict__ GP)
{
    const int tid = threadIdx.x, lane = tid & 63, wid = tid >> 6;
    const int d0 = blockIdx.x * 64 + (wid >> 1) * 32;
    const int jw = blockIdx.y * 32 + (wid & 1) * 16;
    const int ks = blockIdx.z;
    const int l15 = lane & 15, kg = lane >> 4;

    f32x4 acc[3][2];
#pragma unroll
    for (int v = 0; v < 3; ++v) { acc[v][0] = 0.0f; acc[v][1] = 0.0f; }

    for (int tt = 0; tt < 512; tt += 32) {
        const int t0 = ks * 512 + tt;
        bf16x8 a[2];
#pragma unroll
        for (int mi = 0; mi < 2; ++mi)
            a[mi] = *(const bf16x8*)(KT + (size_t)(d0 + 16 * mi + l15) * 8192 + t0 + 8 * kg);

        const ushort_t* vp = VT + (size_t)(jw + l15) * VT_S + t0 + 8 * kg;
        uint4 r0 = *(const uint4*)vp;          // cols +0..7 -> v=2
        uint4 r2 = *(const uint4*)(vp + 2);    // cols +2..9 -> v=0
        uint4 m1;
        m1.x = (r0.x >> 16) | (r2.x << 16);
        m1.y = (r0.y >> 16) | (r2.y << 16);
        m1.z = (r0.z >> 16) | (r2.z << 16);
        m1.w = (r0.w >> 16) | (r2.w << 16);    // cols +1..8 -> v=1
        bf16x8 b2 = __builtin_bit_cast(bf16x8, r0);
        bf16x8 b0 = __builtin_bit_cast(bf16x8, r2);
        bf16x8 b1 = __builtin_bit_cast(bf16x8, m1);
#pragma unroll
        for (int mi = 0; mi < 2; ++mi) {
            acc[0][mi] = __builtin_amdgcn_mfma_f32_16x16x32_bf16(a[mi], b0, acc[0][mi], 0, 0, 0);
            acc[1][mi] = __builtin_amdgcn_mfma_f32_16x16x32_bf16(a[mi], b1, acc[1][mi], 0, 0, 0);
            acc[2][mi] = __builtin_amdgcn_mfma_f32_16x16x32_bf16(a[mi], b2, acc[2][mi], 0, 0, 0);
        }
    }

#pragma unroll
    for (int v = 0; v < 3; ++v) {
        float* gp = GP + (size_t)(ks * 3 + v) * 65536;
#pragma unroll
        for (int mi = 0; mi < 2; ++mi)
#pragma unroll
            for (int r = 0; r < 4; ++r)
                gp[(size_t)(d0 + 16 * mi + 4 * kg + r) * 256 + (jw + l15)]
                    = acc[v][mi][r];
    }
}

// ---------------------------------------------------------------------------
// MTc[u][kb][j][e] = scale * sum_v cw[u][v] * sum_ks GP[ks*3+v][d=kb*8+e][j].
// (unchanged)
// ---------------------------------------------------------------------------
__global__ void combine_m(const float* __restrict__ GP, const float* __restrict__ cw,
                          const float* __restrict__ RED, const float* __restrict__ SVP,
                          const float* __restrict__ cb,
                          ushort_t* __restrict__ MTc, float* __restrict__ SVC)
{
    __shared__ float lds8[8];
    __shared__ float scsh;
    const int d = blockIdx.x, j = threadIdx.x;

    float sq = RED[j], sk = RED[256 + j];
#pragma unroll
    for (int o = 32; o > 0; o >>= 1) { sq += __shfl_down(sq, o); sk += __shfl_down(sk, o); }
    if ((j & 63) == 0) { lds8[j >> 6] = sq; lds8[4 + (j >> 6)] = sk; }

    float g[3] = {0.0f, 0.0f, 0.0f};
    for (int ks = 0; ks < 16; ++ks)
#pragma unroll
        for (int v = 0; v < 3; ++v)
            g[v] += GP[(size_t)(ks * 3 + v) * 65536 + (size_t)d * 256 + j];

    __syncthreads();
    if (j == 0) {
        float SQ = lds8[0] + lds8[1] + lds8[2] + lds8[3];
        float SK = lds8[4] + lds8[5] + lds8[6] + lds8[7];
        scsh = rsqrtf(SQ) * rsqrtf(SK);
    }
    __syncthreads();
    const float sc = scsh;

#pragma unroll
    for (int u = 0; u < 3; ++u) {
        float m = sc * (cw[u * 3 + 0] * g[0] + cw[u * 3 + 1] * g[1] + cw[u * 3 + 2] * g[2]);
        MTc[(size_t)u * 65536 + (size_t)(d >> 3) * 2048 + (size_t)j * 8 + (d & 7)]
            = f2bf(m);
    }
    if (d == 0) {
        float s = 0.0f;
        for (int b = 0; b < 256; ++b) s += SVP[(size_t)b * 256 + j];
        SVC[j] = cb[0] * s;
    }
}

// ---------------------------------------------------------------------------
// attn + LN + z fused. 512 threads (8 waves), 16 rows/block, grid 512.
// z-phase B direct from M1C (coalesced) -> barrier-free z loop.
// ---------------------------------------------------------------------------
__global__ void __launch_bounds__(512)
attn_ln_z_mfma(const ushort_t* __restrict__ QbG, const ushort_t* __restrict__ MTc,
               const float* __restrict__ SVC, const float* __restrict__ x,
               const float* __restrict__ ln1g, const float* __restrict__ ln1b,
               const float* __restrict__ ln2g, const float* __restrict__ ln2b,
               const ushort_t* __restrict__ M1C,
               float* __restrict__ h, float* __restrict__ Z,
               float* __restrict__ ZSP)
{
    __shared__ ushort_t QS[18][264];
    __shared__ float OUT[16][260];
    const int tid = threadIdx.x, lane = tid & 63, wid = tid >> 6;  // wid 0..7
    const int i0 = blockIdx.x * 16;
    const int jw = wid * 32;
    const int l15 = lane & 15, kg = lane >> 4;

    float4 xpre0 = *(const float4*)(x + (size_t)(i0 + wid * 2 + 0) * 256 + lane * 4);
    float4 xpre1 = *(const float4*)(x + (size_t)(i0 + wid * 2 + 1) * 256 + lane * 4);

    {
        int row = tid >> 5, c8 = (tid & 31) * 8;
        *(bf16x8*)(&QS[row][c8]) = *(const bf16x8*)(QbG + (size_t)(i0 + row) * 256 + c8);
        int idx = tid + 512;
        if (idx < 576) {
            row = idx >> 5; c8 = (idx & 31) * 8;
            *(bf16x8*)(&QS[row][c8]) = *(const bf16x8*)(QbG + (size_t)(i0 + row) * 256 + c8);
        }
    }
    __syncthreads();

    f32x4 acc[2];
    acc[0] = 0.0f; acc[1] = 0.0f;

    for (int k0 = 0; k0 < 256; k0 += 32) {
        bf16x8 a[3], b[3][2];
#pragma unroll
        for (int u = 0; u < 3; ++u)
            a[u] = *(const bf16x8*)(&QS[l15 + u][k0 + 8 * kg]);
#pragma unroll
        for (int u = 0; u < 3; ++u)
#pragma unroll
            for (int ni = 0; ni < 2; ++ni)
                b[u][ni] = *(const bf16x8*)(MTc + (size_t)u * 65536
                    + (size_t)((k0 >> 3) + kg) * 2048
                    + (size_t)(jw + 16 * ni + l15) * 8);
#pragma unroll
        for (int ni = 0; ni < 2; ++ni)
#pragma unroll
            for (int u = 0; u < 3; ++u)
                acc[ni] = __builtin_amdgcn_mfma_f32_16x16x32_bf16(
                    a[u], b[u][ni], acc[ni], 0, 0, 0);
    }

#pragma unroll
    for (int ni = 0; ni < 2; ++ni) {
        const int col = jw + 16 * ni + l15;
        const float sv = SVC[col];
#pragma unroll
        for (int r = 0; r < 4; ++r)
            OUT[4 * kg + r][col] = acc[ni][r] + sv;
    }
    __syncthreads();

    const float4 g14 = *(const float4*)(ln1g + lane * 4);
    const float4 b14 = *(const float4*)(ln1b + lane * 4);
    const float4 g24 = *(const float4*)(ln2g + lane * 4);
    const float4 b24 = *(const float4*)(ln2b + lane * 4);
#pragma unroll
    for (int rr = 0; rr < 2; ++rr) {
        const int row_l = wid * 2 + rr;
        const size_t off = (size_t)(i0 + row_l) * 256 + lane * 4;

        float4 a4 = *(const float4*)&OUT[row_l][lane * 4];
        float m = waveSum(a4.x + a4.y + a4.z + a4.w) * (1.0f / D_);
        float4 d4 = make_float4(a4.x - m, a4.y - m, a4.z - m, a4.w - m);
        float var = waveSum(d4.x * d4.x + d4.y * d4.y + d4.z * d4.z + d4.w * d4.w) * (1.0f / D_);
        float rs = rsqrtf(var + EPSF);

        float4 x4 = (rr == 0) ? xpre0 : xpre1;
        float4 h4;
        h4.x = x4.x + d4.x * rs * g14.x + b14.x;
        h4.y = x4.y + d4.y * rs * g14.y + b14.y;
        h4.z = x4.z + d4.z * rs * g14.z + b14.z;
        h4.w = x4.w + d4.w * rs * g14.w + b14.w;
        *(float4*)(h + off) = h4;

        float m2 = waveSum(h4.x + h4.y + h4.z + h4.w) * (1.0f / D_);
        float4 e4 = make_float4(h4.x - m2, h4.y - m2, h4.z - m2, h4.w - m2);
        float v2 = waveSum(e4.x * e4.x + e4.y * e4.y + e4.z * e4.z + e4.w * e4.w) * (1.0f / D_);
        float rs2 = rsqrtf(v2 + EPSF);

        float4 o4;
        o4.x = e4.x * rs2 * g24.x + b24.x;
        o4.y = e4.y * rs2 * g24.y + b24.y;
        o4.z = e4.z * rs2 * g24.z + b24.z;
        o4.w = e4.w * rs2 * g24.w + b24.w;
        *(float4*)&OUT[row_l][lane * 4] = o4;
    }
    __syncthreads();

    // ---- z = l2 @ m1w^T, barrier-free: A from OUT (LDS), B from M1C ----
    const int jz = wid * 16;
    f32x4 zacc;
    zacc = 0.0f;

    for (int k0 = 0; k0 < 256; k0 += 32) {
        bf16x8 a, b;
        {
            const float* lp = &OUT[l15][k0 + 8 * kg];
            a = cvt8(*(const float4*)lp, *(const float4*)(lp + 4));
        }
        b = *(const bf16x8*)(M1C + (size_t)((k0 >> 3) + kg) * 1024
                                  + (size_t)(jz + l15) * 8);
        zacc = __builtin_amdgcn_mfma_f32_16x16x32_bf16(a, b, zacc, 0, 0, 0);
    }

    float s = 0.0f, q = 0.0f;
    const int col = jz + l15;
#pragma unroll
    for (int r = 0; r < 4; ++r) {
        float zv = zacc[r];
        Z[(size_t)(i0 + 4 * kg + r) * 128 + col] = zv;
        s += zv;
        q = fmaf(zv, zv, q);
    }
    s += __shfl_xor(s, 16); s += __shfl_xor(s, 32);
    q += __shfl_xor(q, 16); q += __shfl_xor(q, 32);
    if (kg == 0) {
        ZSP[(size_t)blockIdx.x * 256 + col] = s;
        ZSP[(size_t)blockIdx.x * 256 + 128 + col] = q;
    }
}

// ---------------------------------------------------------------------------
// bn_reduce: BNS[c] = sum_b ZSP[b][c]  (unchanged)
// ---------------------------------------------------------------------------
__global__ void bn_reduce(const float* __restrict__ ZSP, float* __restrict__ BNS)
{
    __shared__ float red[8][32];
    const int tid = threadIdx.x;
    const int c0 = blockIdx.x * 32;
    const int cl = tid & 31, g = tid >> 5;
    float s = 0.0f;
    for (int b = g; b < 512; b += 8)
        s += ZSP[(size_t)b * 256 + c0 + cl];
    red[g][cl] = s;
    __syncthreads();
    if (tid < 32) {
        float t = 0.0f;
#pragma unroll
        for (int g2 = 0; g2 < 8; ++g2) t += red[g2][tid];
        BNS[c0 + tid] = t;
    }
}

// ---------------------------------------------------------------------------
// out = h + relu(z*a+b) @ m2w^T. 512 threads, 16 rows, grid 512.
// B direct-coalesced from M2C (no staging, no K-loop barriers).
// ---------------------------------------------------------------------------
__global__ void __launch_bounds__(512)
gemm_out_mfma(const float* __restrict__ Z, const ushort_t* __restrict__ M2C,
              const float* __restrict__ BNS,
              const float* __restrict__ bng, const float* __restrict__ bnb,
              float* __restrict__ out)
{
    __shared__ float bnA[128], bnB[128];
    __shared__ ushort_t XS[16][136];
    const int tid = threadIdx.x, lane = tid & 63, wid = tid >> 6;
    const int i0 = blockIdx.x * 16;
    const int jw = wid * 32;
    const int l15 = lane & 15, kg = lane >> 4;

    float oprev[2][4];
#pragma unroll
    for (int ni = 0; ni < 2; ++ni)
#pragma unroll
        for (int r = 0; r < 4; ++r)
            oprev[ni][r] = out[(size_t)(i0 + 4 * kg + r) * 256 + jw + 16 * ni + l15];

    if (tid < 128) {
        float s = BNS[tid], q = BNS[128 + tid];
        float mu = s * (1.0f / N_);
        float var = q * (1.0f / N_) - mu * mu;
        float aa = rsqrtf(var + EPSF) * bng[tid];
        bnA[tid] = aa;
        bnB[tid] = bnb[tid] - mu * aa;
    }
    __syncthreads();

    if (tid < 256) {
        int row = tid >> 4, c8 = (tid & 15) * 8;
        const float* zp = Z + (size_t)(i0 + row) * 128 + c8;
        float4 f0 = *(const float4*)zp;
        float4 f1 = *(const float4*)(zp + 4);
        float4 g0, g1;
        g0.x = fmaxf(fmaf(f0.x, bnA[c8 + 0], bnB[c8 + 0]), 0.0f);
        g0.y = fmaxf(fmaf(f0.y, bnA[c8 + 1], bnB[c8 + 1]), 0.0f);
        g0.z = fmaxf(fmaf(f0.z, bnA[c8 + 2], bnB[c8 + 2]), 0.0f);
        g0.w = fmaxf(fmaf(f0.w, bnA[c8 + 3], bnB[c8 + 3]), 0.0f);
        g1.x = fmaxf(fmaf(f1.x, bnA[c8 + 4], bnB[c8 + 4]), 0.0f);
        g1.y = fmaxf(fmaf(f1.y, bnA[c8 + 5], bnB[c8 + 5]), 0.0f);
        g1.z = fmaxf(fmaf(f1.z, bnA[c8 + 6], bnB[c8 + 6]), 0.0f);
        g1.w = fmaxf(fmaf(f1.w, bnA[c8 + 7], bnB[c8 + 7]), 0.0f);
        *(bf16x8*)(&XS[row][c8]) = cvt8(g0, g1);
    }
    __syncthreads();

    f32x4 acc[2];
    acc[0] = 0.0f; acc[1] = 0.0f;

    for (int k0 = 0; k0 < 128; k0 += 32) {
        bf16x8 a = *(const bf16x8*)(&XS[l15][k0 + 8 * kg]);
        bf16x8 b[2];
#pragma unroll
        for (int ni = 0; ni < 2; ++ni)
            b[ni] = *(const bf16x8*)(M2C + (size_t)((k0 >> 3) + kg) * 2048
                                          + (size_t)(jw + 16 * ni + l15) * 8);
#pragma unroll
        for (int ni = 0; ni < 2; ++ni)
            acc[ni] = __builtin_amdgcn_mfma_f32_16x16x32_bf16(a, b[ni], acc[ni], 0, 0, 0);
    }

#pragma unroll
    for (int ni = 0; ni < 2; ++ni)
#pragma unroll
        for (int r = 0; r < 4; ++r) {
            const size_t idx = (size_t)(i0 + 4 * kg + r) * 256
                             + (jw + 16 * ni + l15);
            out[idx] = oprev[ni][r] + acc[ni][r];
        }
}

// ---------------------------------------------------------------------------
extern "C" void kernel_launch(void* const* d_in, const int* in_sizes, int n_in,
                              void* d_out, int out_size, void* d_ws, size_t ws_size,
                              hipStream_t stream)
{
    const float* x    = (const float*)d_in[0];
    const float* wq   = (const float*)d_in[1];
    const float* bq   = (const float*)d_in[2];
    const float* wk   = (const float*)d_in[3];
    const float* bk   = (const float*)d_in[4];
    const float* wv   = (const float*)d_in[5];
    const float* bv   = (const float*)d_in[6];
    const float* cw   = (const float*)d_in[7];
    const float* cb   = (const float*)d_in[8];
    const float* m1w  = (const float*)d_in[9];
    const float* m2w  = (const float*)d_in[10];
    const float* bng  = (const float*)d_in[11];
    const float* bnb  = (const float*)d_in[12];
    const float* ln1g = (const float*)d_in[13];
    const float* ln1b = (const float*)d_in[14];
    const float* ln2g = (const float*)d_in[15];
    const float* ln2b = (const float*)d_in[16];

    float* outF = (float*)d_out;
    char*  wsb  = (char*)d_ws;
    if (ws_size < WS_NEED) return;

    ushort_t* QbG = (ushort_t*)(wsb + OFF_QB);
    ushort_t* KT  = (ushort_t*)(wsb + OFF_KT);
    ushort_t* VT  = (ushort_t*)(wsb + OFF_VT);
    float*    GP  = (float*)(wsb + OFF_GP);
    ushort_t* MTc = (ushort_t*)(wsb + OFF_MT);
    float*    SVP = (float*)(wsb + OFF_SVP);
    float*    SVC = (float*)(wsb + OFF_SVC);
    float*    RED = (float*)(wsb + OFF_RED);
    float*    ZSP = (float*)(wsb + OFF_ZSP);
    float*    BNS = (float*)(wsb + OFF_BNS);
    ushort_t* WC  = (ushort_t*)(wsb + OFF_WC);
    ushort_t* M1C = (ushort_t*)(wsb + OFF_M1C);
    ushort_t* M2C = (ushort_t*)(wsb + OFF_M2C);
    float*    Z   = (float*)(wsb + OFF_GP);   // GP dead after combine_m

    const dim3 b256(256);
    const dim3 b512(512);

    prep_w<<<145, b256, 0, stream>>>(wq, wk, wv, m1w, m2w, WC, M1C, M2C, QbG, VT);
    qkv_mfma<<<dim3(256, 3), b256, 0, stream>>>(x, WC, bq, bk, bv,
                                                QbG, KT, VT, RED, SVP);
    g_mfma<<<dim3(4, 8, 16), b256, 0, stream>>>(KT, VT, GP);
    combine_m<<<256, b256, 0, stream>>>(GP, cw, RED, SVP, cb, MTc, SVC);
    attn_ln_z_mfma<<<512, b512, 0, stream>>>(QbG, MTc, SVC, x,
                                             ln1g, ln1b, ln2g, ln2b, M1C,
                                             outF, Z, ZSP);
    bn_reduce<<<8, b256, 0, stream>>>(ZSP, BNS);
    gemm_out_mfma<<<512, b512, 0, stream>>>(Z, M2C, BNS, bng, bnb, outF);
}

// Round 18
// 82.082 us; speedup vs baseline: 1.5972x; 1.0790x over previous
//
#include <hip/hip_runtime.h>
#include <hip/hip_bf16.h>
#include <math.h>

// ---------------------------------------------------------------------------
// GraphBased_selfAttnLayer — collapsed attention path, 7 launches.
//
//   G_v  = (S_{v-1} K)^T V            (MFMA, K-dim 8192, coalesced KTC/VTC)
//   M_u  = scale * sum_v cw[u][v] G_v   -> MTc fragment-coalesced layout
//   attn = sum_u S_{u-1}(Q M_u) + cb*colsum(V); h = x + LN1(attn);
//   l2 = LN2(h) (LDS only); z = l2@m1w^T (fused) ; BN (2-stage) ;
//   out = h + relu(z*a+b) @ m2w^T
//
// Launches: prep -> qkv -> g -> combine -> attn+LN+z -> bn_reduce -> out.
// ALL MFMA fragment operands (A of g via KTC, B everywhere via WC/M1C/M2C/
// MTc/VTC) are in fragment-coalesced layouts: frag load = 16 consecutive
// 16B chunks per 16-lane group. No row-stride request amplification left.
//
// Layouts:
//   WC/M1C/M2C/MTc[kb][j][e] = W[j][k=kb*8+e]       (bf16)
//   KTC[tb][d][e]  = K[t=tb*8+e][d]                 (bf16)
//   VTC[cb][j][e]  = V[c-1][j], c=cb*8+e            (bf16, c=0/8193 guard=0)
//   XB[i][k]       = bf16(x[i][k])
//
// ws (bytes):
//   QbG bf16 [8194][256]     @ 0
//   KTC bf16 [1024][256][8]  @  4,195,328
//   VTC bf16 [1025][256][8]  @  8,389,632
//   GP  f32 [48][256][256]   @ 12,588,032  <- after combine: Z f32 [8192][128]
//   MTc bf16 [3][32][256][8] @ 25,170,944
//   SVP f32 [256][256]       @ 25,564,160
//   SVC f32 [256]            @ 25,826,304
//   RED f32 [512]            @ 25,827,328
//   ZSP f32 [512][256]       @ 25,829,376
//   BNS f32 [256]            @ 26,353,664
//   WC  bf16 [3][32][256][8] @ 26,354,688
//   M1C bf16 [32][128][8]    @ 26,747,904
//   M2C bf16 [16][256][8]    @ 26,813,440
//   XB  bf16 [8192][256]     @ 26,878,976   (ends 31,073,280)
// ---------------------------------------------------------------------------

#define N_ 8192
#define D_ 256
#define H_ 128
#define EPSF 1e-5f

typedef unsigned short ushort_t;
typedef unsigned int uint_t;
typedef __attribute__((ext_vector_type(8))) short bf16x8;
typedef __attribute__((ext_vector_type(4))) short bf16x4;
typedef __attribute__((ext_vector_type(4))) float f32x4;

static const size_t OFF_QB  = 0;
static const size_t OFF_KT  = 4195328;
static const size_t OFF_VT  = 8389632;
static const size_t OFF_GP  = 12588032;
static const size_t OFF_MT  = 25170944;
static const size_t OFF_SVP = 25564160;
static const size_t OFF_SVC = 25826304;
static const size_t OFF_RED = 25827328;
static const size_t OFF_ZSP = 25829376;
static const size_t OFF_BNS = 26353664;
static const size_t OFF_WC  = 26354688;
static const size_t OFF_M1C = 26747904;
static const size_t OFF_M2C = 26813440;
static const size_t OFF_XB  = 26878976;
static const size_t WS_NEED = 31073280;

__device__ __forceinline__ ushort_t f2bf(float f) {
    __hip_bfloat16 h = __float2bfloat16(f);
    return reinterpret_cast<ushort_t&>(h);
}

__device__ __forceinline__ bf16x8 cvt8(float4 f0, float4 f1) {
    bf16x8 o;
    o[0] = (short)f2bf(f0.x); o[1] = (short)f2bf(f0.y);
    o[2] = (short)f2bf(f0.z); o[3] = (short)f2bf(f0.w);
    o[4] = (short)f2bf(f1.x); o[5] = (short)f2bf(f1.y);
    o[6] = (short)f2bf(f1.z); o[7] = (short)f2bf(f1.w);
    return o;
}

__device__ __forceinline__ float waveSum(float v)
{
#pragma unroll
    for (int o = 32; o > 0; o >>= 1) v += __shfl_xor(v, o);
    return v;
}

// ---------------------------------------------------------------------------
// prep: weights -> WC/M1C/M2C, x -> XB (bf16), zero QbG/VTC guards.
// grid 1169 x 256.
// ---------------------------------------------------------------------------
__global__ void prep_w(const float* __restrict__ wq, const float* __restrict__ wk,
                       const float* __restrict__ wv, const float* __restrict__ m1w,
                       const float* __restrict__ m2w, const float* __restrict__ x,
                       ushort_t* __restrict__ WC, ushort_t* __restrict__ M1C,
                       ushort_t* __restrict__ M2C, ushort_t* __restrict__ XB,
                       ushort_t* __restrict__ QbG, ushort_t* __restrict__ VTC)
{
    const int bid = blockIdx.x, tid = threadIdx.x;
    if (bid < 96) {
        const int sel = bid >> 5, kb = bid & 31;
        const float* W = (sel == 0) ? wq : ((sel == 1) ? wk : wv);
        const float* p = W + (size_t)tid * 256 + kb * 8;
        *(bf16x8*)(WC + (size_t)sel * 65536 + (size_t)kb * 2048 + (size_t)tid * 8)
            = cvt8(*(const float4*)p, *(const float4*)(p + 4));
    } else if (bid < 128) {
        const int kb = bid - 96;
        if (tid < 128) {
            const float* p = m1w + (size_t)tid * 256 + kb * 8;
            *(bf16x8*)(M1C + (size_t)kb * 1024 + (size_t)tid * 8)
                = cvt8(*(const float4*)p, *(const float4*)(p + 4));
        }
    } else if (bid < 144) {
        const int kb = bid - 128;
        const float* p = m2w + (size_t)tid * 128 + kb * 8;
        *(bf16x8*)(M2C + (size_t)kb * 2048 + (size_t)tid * 8)
            = cvt8(*(const float4*)p, *(const float4*)(p + 4));
    } else if (bid == 144) {
        QbG[tid] = 0; QbG[(size_t)8193 * 256 + tid] = 0;
        VTC[(size_t)tid * 8] = 0;                         // c = 0  (cb 0, e 0)
        VTC[((size_t)1024 * 256 + tid) * 8 + 1] = 0;      // c = 8193 (cb 1024, e 1)
    } else {
        const size_t lin = (size_t)(bid - 145) * 2048 + (size_t)tid * 8;
        const float* p = x + lin;
        *(bf16x8*)(XB + lin) = cvt8(*(const float4*)p, *(const float4*)(p + 4));
    }
}

// ---------------------------------------------------------------------------
// qkv via MFMA: A (x tile) LDS-staged once from XB (bf16 copy);
// B direct-coalesced from WC. grid (256, 3). No K-loop barriers.
// Epilogues write Q row-major (guarded), K -> KTC, V -> VTC (+1 shift).
// ---------------------------------------------------------------------------
__global__ void __launch_bounds__(256)
qkv_mfma(const ushort_t* __restrict__ XB, const ushort_t* __restrict__ WC,
         const float* __restrict__ bq, const float* __restrict__ bk,
         const float* __restrict__ bv,
         ushort_t* __restrict__ QbG, ushort_t* __restrict__ KTC,
         ushort_t* __restrict__ VTC,
         float* __restrict__ RED, float* __restrict__ SVP)
{
    __shared__ ushort_t XS[32][264];
    __shared__ float lds4[4];
    const int tid = threadIdx.x, lane = tid & 63, wid = tid >> 6;
    const int sel = blockIdx.y;
    const int i0 = blockIdx.x * 32;
    const int jw = wid * 64;
    const int l15 = lane & 15, kg = lane >> 4;
    const ushort_t* Wc = WC + (size_t)sel * 65536;
    const float* B = (sel == 0) ? bq : ((sel == 1) ? bk : bv);

#pragma unroll
    for (int p = 0; p < 4; ++p) {
        int lin = p * 256 + tid;
        int row = lin >> 5;
        int c8  = (lin & 31) * 8;
        *(bf16x8*)(&XS[row][c8]) = *(const bf16x8*)(XB + (size_t)(i0 + row) * 256 + c8);
    }
    __syncthreads();

    f32x4 acc[2][4];
#pragma unroll
    for (int mi = 0; mi < 2; ++mi)
#pragma unroll
        for (int ni = 0; ni < 4; ++ni) acc[mi][ni] = 0.0f;

    for (int k0 = 0; k0 < 256; k0 += 32) {
        bf16x8 a[2], b[4];
#pragma unroll
        for (int mi = 0; mi < 2; ++mi)
            a[mi] = *(const bf16x8*)(&XS[16 * mi + l15][k0 + 8 * kg]);
#pragma unroll
        for (int ni = 0; ni < 4; ++ni)
            b[ni] = *(const bf16x8*)(Wc + (size_t)((k0 >> 3) + kg) * 2048
                                        + (size_t)(jw + 16 * ni + l15) * 8);
#pragma unroll
        for (int mi = 0; mi < 2; ++mi)
#pragma unroll
            for (int ni = 0; ni < 4; ++ni)
                acc[mi][ni] = __builtin_amdgcn_mfma_f32_16x16x32_bf16(a[mi], b[ni], acc[mi][ni], 0, 0, 0);
    }

    float ssq = 0.0f;
    float colp[4] = {0.0f, 0.0f, 0.0f, 0.0f};

    if (sel == 0) {
#pragma unroll
        for (int mi = 0; mi < 2; ++mi)
#pragma unroll
            for (int ni = 0; ni < 4; ++ni) {
                const int col = jw + 16 * ni + l15;
                const float bias = B[col];
#pragma unroll
                for (int r = 0; r < 4; ++r) {
                    const int row = i0 + 16 * mi + 4 * kg + r;
                    float val = acc[mi][ni][r] + bias;
                    QbG[(size_t)(row + 1) * 256 + col] = f2bf(val);
                    ssq = fmaf(val, val, ssq);
                }
            }
    } else if (sel == 1) {
        // K -> KTC[tb][d][e]: tb = t>>3; t = i0+16mi+4kg+r; (t&7) in {0,4}
#pragma unroll
        for (int mi = 0; mi < 2; ++mi)
#pragma unroll
            for (int ni = 0; ni < 4; ++ni) {
                const int col = jw + 16 * ni + l15;   // d
                const float bias = B[col];
                const int tb = i0 + 16 * mi + 4 * kg;
                bf16x4 pk;
#pragma unroll
                for (int r = 0; r < 4; ++r) {
                    float val = acc[mi][ni][r] + bias;
                    ssq = fmaf(val, val, ssq);
                    pk[r] = (short)f2bf(val);
                }
                *(bf16x4*)(KTC + ((size_t)(tb >> 3) * 256 + col) * 8 + (tb & 7)) = pk;
            }
    } else {
        // V -> VTC[cb][j][e] with c = t+1: e0 = (tb&7)+1 in {1,5}
#pragma unroll
        for (int mi = 0; mi < 2; ++mi)
#pragma unroll
            for (int ni = 0; ni < 4; ++ni) {
                const int col = jw + 16 * ni + l15;   // j
                const float bias = B[col];
                const int tb = i0 + 16 * mi + 4 * kg;
                const int cb = tb >> 3, e0 = (tb & 7) + 1;
                float v0 = acc[mi][ni][0] + bias, v1 = acc[mi][ni][1] + bias;
                float v2 = acc[mi][ni][2] + bias, v3 = acc[mi][ni][3] + bias;
                colp[ni] += v0 + v1 + v2 + v3;
                ushort_t* p = VTC + ((size_t)cb * 256 + col) * 8 + e0;
                p[0] = f2bf(v0);
                *(uint_t*)(p + 1) = (uint_t)f2bf(v1) | ((uint_t)f2bf(v2) << 16);
                ushort_t v3b = f2bf(v3);
                if (e0 == 5)
                    VTC[((size_t)(cb + 1) * 256 + col) * 8] = v3b;   // e = 0 of next cb
                else
                    p[3] = v3b;                                       // e = 4
            }
    }

    if (sel < 2) {
        float s = ssq;
#pragma unroll
        for (int o = 32; o > 0; o >>= 1) s += __shfl_down(s, o);
        if (lane == 0) lds4[wid] = s;
        __syncthreads();
        if (tid == 0)
            RED[sel * 256 + blockIdx.x] = lds4[0] + lds4[1] + lds4[2] + lds4[3];
    } else {
#pragma unroll
        for (int ni = 0; ni < 4; ++ni) {
            float v = colp[ni];
            v += __shfl_xor(v, 16);
            v += __shfl_xor(v, 32);
            if (kg == 0)
                SVP[(size_t)blockIdx.x * 256 + jw + 16 * ni + l15] = v;
        }
    }
}

// ---------------------------------------------------------------------------
// G_v[d][j] = sum_t K[t][d] * V[t+1-v][j].  grid (4, 8, 16) = 512 blocks.
// A from KTC, V from VTC — both fragment-coalesced; shifts via reg splice.
// ---------------------------------------------------------------------------
__global__ void __launch_bounds__(256)
g_mfma(const ushort_t* __restrict__ KTC, const ushort_t* __restrict__ VTC,
       float* __restrict__ GP)
{
    const int tid = threadIdx.x, lane = tid & 63, wid = tid >> 6;
    const int d0 = blockIdx.x * 64 + (wid >> 1) * 32;
    const int jw = blockIdx.y * 32 + (wid & 1) * 16;
    const int ks = blockIdx.z;
    const int l15 = lane & 15, kg = lane >> 4;

    f32x4 acc[3][2];
#pragma unroll
    for (int v = 0; v < 3; ++v) { acc[v][0] = 0.0f; acc[v][1] = 0.0f; }

    for (int tt = 0; tt < 512; tt += 32) {
        const int t0 = ks * 512 + tt;
        const int cb0 = (t0 >> 3) + kg;
        bf16x8 a[2];
#pragma unroll
        for (int mi = 0; mi < 2; ++mi)
            a[mi] = *(const bf16x8*)(KTC + ((size_t)cb0 * 256 + (d0 + 16 * mi + l15)) * 8);

        const int j = jw + l15;
        uint4 r0 = *(const uint4*)(VTC + ((size_t)cb0 * 256 + j) * 8);        // c .. c+7
        uint_t rx = *(const uint_t*)(VTC + ((size_t)(cb0 + 1) * 256 + j) * 8); // c+8, c+9
        uint4 r2;                                   // c+2 .. c+9  (v=0)
        r2.x = r0.y; r2.y = r0.z; r2.z = r0.w; r2.w = rx;
        uint4 m1;                                   // c+1 .. c+8  (v=1)
        m1.x = (r0.x >> 16) | (r2.x << 16);
        m1.y = (r0.y >> 16) | (r2.y << 16);
        m1.z = (r0.z >> 16) | (r2.z << 16);
        m1.w = (r0.w >> 16) | (r2.w << 16);
        bf16x8 b2 = __builtin_bit_cast(bf16x8, r0);
        bf16x8 b0 = __builtin_bit_cast(bf16x8, r2);
        bf16x8 b1 = __builtin_bit_cast(bf16x8, m1);
#pragma unroll
        for (int mi = 0; mi < 2; ++mi) {
            acc[0][mi] = __builtin_amdgcn_mfma_f32_16x16x32_bf16(a[mi], b0, acc[0][mi], 0, 0, 0);
            acc[1][mi] = __builtin_amdgcn_mfma_f32_16x16x32_bf16(a[mi], b1, acc[1][mi], 0, 0, 0);
            acc[2][mi] = __builtin_amdgcn_mfma_f32_16x16x32_bf16(a[mi], b2, acc[2][mi], 0, 0, 0);
        }
    }

#pragma unroll
    for (int v = 0; v < 3; ++v) {
        float* gp = GP + (size_t)(ks * 3 + v) * 65536;
#pragma unroll
        for (int mi = 0; mi < 2; ++mi)
#pragma unroll
            for (int r = 0; r < 4; ++r)
                gp[(size_t)(d0 + 16 * mi + 4 * kg + r) * 256 + (jw + l15)]
                    = acc[v][mi][r];
    }
}

// ---------------------------------------------------------------------------
// MTc[u][kb][j][e] = scale * sum_v cw[u][v] * sum_ks GP[ks*3+v][d=kb*8+e][j].
// (unchanged)
// ---------------------------------------------------------------------------
__global__ void combine_m(const float* __restrict__ GP, const float* __restrict__ cw,
                          const float* __restrict__ RED, const float* __restrict__ SVP,
                          const float* __restrict__ cb,
                          ushort_t* __restrict__ MTc, float* __restrict__ SVC)
{
    __shared__ float lds8[8];
    __shared__ float scsh;
    const int d = blockIdx.x, j = threadIdx.x;

    float sq = RED[j], sk = RED[256 + j];
#pragma unroll
    for (int o = 32; o > 0; o >>= 1) { sq += __shfl_down(sq, o); sk += __shfl_down(sk, o); }
    if ((j & 63) == 0) { lds8[j >> 6] = sq; lds8[4 + (j >> 6)] = sk; }

    float g[3] = {0.0f, 0.0f, 0.0f};
    for (int ks = 0; ks < 16; ++ks)
#pragma unroll
        for (int v = 0; v < 3; ++v)
            g[v] += GP[(size_t)(ks * 3 + v) * 65536 + (size_t)d * 256 + j];

    __syncthreads();
    if (j == 0) {
        float SQ = lds8[0] + lds8[1] + lds8[2] + lds8[3];
        float SK = lds8[4] + lds8[5] + lds8[6] + lds8[7];
        scsh = rsqrtf(SQ) * rsqrtf(SK);
    }
    __syncthreads();
    const float sc = scsh;

#pragma unroll
    for (int u = 0; u < 3; ++u) {
        float m = sc * (cw[u * 3 + 0] * g[0] + cw[u * 3 + 1] * g[1] + cw[u * 3 + 2] * g[2]);
        MTc[(size_t)u * 65536 + (size_t)(d >> 3) * 2048 + (size_t)j * 8 + (d & 7)]
            = f2bf(m);
    }
    if (d == 0) {
        float s = 0.0f;
        for (int b = 0; b < 256; ++b) s += SVP[(size_t)b * 256 + j];
        SVC[j] = cb[0] * s;
    }
}

// ---------------------------------------------------------------------------
// attn + LN + z fused. 512 threads (8 waves), 16 rows/block, grid 512.
// (unchanged from round 17)
// ---------------------------------------------------------------------------
__global__ void __launch_bounds__(512)
attn_ln_z_mfma(const ushort_t* __restrict__ QbG, const ushort_t* __restrict__ MTc,
               const float* __restrict__ SVC, const float* __restrict__ x,
               const float* __restrict__ ln1g, const float* __restrict__ ln1b,
               const float* __restrict__ ln2g, const float* __restrict__ ln2b,
               const ushort_t* __restrict__ M1C,
               float* __restrict__ h, float* __restrict__ Z,
               float* __restrict__ ZSP)
{
    __shared__ ushort_t QS[18][264];
    __shared__ float OUT[16][260];
    const int tid = threadIdx.x, lane = tid & 63, wid = tid >> 6;  // wid 0..7
    const int i0 = blockIdx.x * 16;
    const int jw = wid * 32;
    const int l15 = lane & 15, kg = lane >> 4;

    float4 xpre0 = *(const float4*)(x + (size_t)(i0 + wid * 2 + 0) * 256 + lane * 4);
    float4 xpre1 = *(const float4*)(x + (size_t)(i0 + wid * 2 + 1) * 256 + lane * 4);

    {
        int row = tid >> 5, c8 = (tid & 31) * 8;
        *(bf16x8*)(&QS[row][c8]) = *(const bf16x8*)(QbG + (size_t)(i0 + row) * 256 + c8);
        int idx = tid + 512;
        if (idx < 576) {
            row = idx >> 5; c8 = (idx & 31) * 8;
            *(bf16x8*)(&QS[row][c8]) = *(const bf16x8*)(QbG + (size_t)(i0 + row) * 256 + c8);
        }
    }
    __syncthreads();

    f32x4 acc[2];
    acc[0] = 0.0f; acc[1] = 0.0f;

    for (int k0 = 0; k0 < 256; k0 += 32) {
        bf16x8 a[3], b[3][2];
#pragma unroll
        for (int u = 0; u < 3; ++u)
            a[u] = *(const bf16x8*)(&QS[l15 + u][k0 + 8 * kg]);
#pragma unroll
        for (int u = 0; u < 3; ++u)
#pragma unroll
            for (int ni = 0; ni < 2; ++ni)
                b[u][ni] = *(const bf16x8*)(MTc + (size_t)u * 65536
                    + (size_t)((k0 >> 3) + kg) * 2048
                    + (size_t)(jw + 16 * ni + l15) * 8);
#pragma unroll
        for (int ni = 0; ni < 2; ++ni)
#pragma unroll
            for (int u = 0; u < 3; ++u)
                acc[ni] = __builtin_amdgcn_mfma_f32_16x16x32_bf16(
                    a[u], b[u][ni], acc[ni], 0, 0, 0);
    }

#pragma unroll
    for (int ni = 0; ni < 2; ++ni) {
        const int col = jw + 16 * ni + l15;
        const float sv = SVC[col];
#pragma unroll
        for (int r = 0; r < 4; ++r)
            OUT[4 * kg + r][col] = acc[ni][r] + sv;
    }
    __syncthreads();

    const float4 g14 = *(const float4*)(ln1g + lane * 4);
    const float4 b14 = *(const float4*)(ln1b + lane * 4);
    const float4 g24 = *(const float4*)(ln2g + lane * 4);
    const float4 b24 = *(const float4*)(ln2b + lane * 4);
#pragma unroll
    for (int rr = 0; rr < 2; ++rr) {
        const int row_l = wid * 2 + rr;
        const size_t off = (size_t)(i0 + row_l) * 256 + lane * 4;

        float4 a4 = *(const float4*)&OUT[row_l][lane * 4];
        float m = waveSum(a4.x + a4.y + a4.z + a4.w) * (1.0f / D_);
        float4 d4 = make_float4(a4.x - m, a4.y - m, a4.z - m, a4.w - m);
        float var = waveSum(d4.x * d4.x + d4.y * d4.y + d4.z * d4.z + d4.w * d4.w) * (1.0f / D_);
        float rs = rsqrtf(var + EPSF);

        float4 x4 = (rr == 0) ? xpre0 : xpre1;
        float4 h4;
        h4.x = x4.x + d4.x * rs * g14.x + b14.x;
        h4.y = x4.y + d4.y * rs * g14.y + b14.y;
        h4.z = x4.z + d4.z * rs * g14.z + b14.z;
        h4.w = x4.w + d4.w * rs * g14.w + b14.w;
        *(float4*)(h + off) = h4;

        float m2 = waveSum(h4.x + h4.y + h4.z + h4.w) * (1.0f / D_);
        float4 e4 = make_float4(h4.x - m2, h4.y - m2, h4.z - m2, h4.w - m2);
        float v2 = waveSum(e4.x * e4.x + e4.y * e4.y + e4.z * e4.z + e4.w * e4.w) * (1.0f / D_);
        float rs2 = rsqrtf(v2 + EPSF);

        float4 o4;
        o4.x = e4.x * rs2 * g24.x + b24.x;
        o4.y = e4.y * rs2 * g24.y + b24.y;
        o4.z = e4.z * rs2 * g24.z + b24.z;
        o4.w = e4.w * rs2 * g24.w + b24.w;
        *(float4*)&OUT[row_l][lane * 4] = o4;
    }
    __syncthreads();

    // ---- z = l2 @ m1w^T, barrier-free: A from OUT (LDS), B from M1C ----
    const int jz = wid * 16;
    f32x4 zacc;
    zacc = 0.0f;

    for (int k0 = 0; k0 < 256; k0 += 32) {
        bf16x8 a, b;
        {
            const float* lp = &OUT[l15][k0 + 8 * kg];
            a = cvt8(*(const float4*)lp, *(const float4*)(lp + 4));
        }
        b = *(const bf16x8*)(M1C + (size_t)((k0 >> 3) + kg) * 1024
                                  + (size_t)(jz + l15) * 8);
        zacc = __builtin_amdgcn_mfma_f32_16x16x32_bf16(a, b, zacc, 0, 0, 0);
    }

    float s = 0.0f, q = 0.0f;
    const int col = jz + l15;
#pragma unroll
    for (int r = 0; r < 4; ++r) {
        float zv = zacc[r];
        Z[(size_t)(i0 + 4 * kg + r) * 128 + col] = zv;
        s += zv;
        q = fmaf(zv, zv, q);
    }
    s += __shfl_xor(s, 16); s += __shfl_xor(s, 32);
    q += __shfl_xor(q, 16); q += __shfl_xor(q, 32);
    if (kg == 0) {
        ZSP[(size_t)blockIdx.x * 256 + col] = s;
        ZSP[(size_t)blockIdx.x * 256 + 128 + col] = q;
    }
}

// ---------------------------------------------------------------------------
// bn_reduce: BNS[c] = sum_b ZSP[b][c]  (unchanged)
// ---------------------------------------------------------------------------
__global__ void bn_reduce(const float* __restrict__ ZSP, float* __restrict__ BNS)
{
    __shared__ float red[8][32];
    const int tid = threadIdx.x;
    const int c0 = blockIdx.x * 32;
    const int cl = tid & 31, g = tid >> 5;
    float s = 0.0f;
    for (int b = g; b < 512; b += 8)
        s += ZSP[(size_t)b * 256 + c0 + cl];
    red[g][cl] = s;
    __syncthreads();
    if (tid < 32) {
        float t = 0.0f;
#pragma unroll
        for (int g2 = 0; g2 < 8; ++g2) t += red[g2][tid];
        BNS[c0 + tid] = t;
    }
}

// ---------------------------------------------------------------------------
// out = h + relu(z*a+b) @ m2w^T. (unchanged from round 17)
// ---------------------------------------------------------------------------
__global__ void __launch_bounds__(512)
gemm_out_mfma(const float* __restrict__ Z, const ushort_t* __restrict__ M2C,
              const float* __restrict__ BNS,
              const float* __restrict__ bng, const float* __restrict__ bnb,
              float* __restrict__ out)
{
    __shared__ float bnA[128], bnB[128];
    __shared__ ushort_t XS[16][136];
    const int tid = threadIdx.x, lane = tid & 63, wid = tid >> 6;
    const int i0 = blockIdx.x * 16;
    const int jw = wid * 32;
    const int l15 = lane & 15, kg = lane >> 4;

    float oprev[2][4];
#pragma unroll
    for (int ni = 0; ni < 2; ++ni)
#pragma unroll
        for (int r = 0; r < 4; ++r)
            oprev[ni][r] = out[(size_t)(i0 + 4 * kg + r) * 256 + jw + 16 * ni + l15];

    if (tid < 128) {
        float s = BNS[tid], q = BNS[128 + tid];
        float mu = s * (1.0f / N_);
        float var = q * (1.0f / N_) - mu * mu;
        float aa = rsqrtf(var + EPSF) * bng[tid];
        bnA[tid] = aa;
        bnB[tid] = bnb[tid] - mu * aa;
    }
    __syncthreads();

    if (tid < 256) {
        int row = tid >> 4, c8 = (tid & 15) * 8;
        const float* zp = Z + (size_t)(i0 + row) * 128 + c8;
        float4 f0 = *(const float4*)zp;
        float4 f1 = *(const float4*)(zp + 4);
        float4 g0, g1;
        g0.x = fmaxf(fmaf(f0.x, bnA[c8 + 0], bnB[c8 + 0]), 0.0f);
        g0.y = fmaxf(fmaf(f0.y, bnA[c8 + 1], bnB[c8 + 1]), 0.0f);
        g0.z = fmaxf(fmaf(f0.z, bnA[c8 + 2], bnB[c8 + 2]), 0.0f);
        g0.w = fmaxf(fmaf(f0.w, bnA[c8 + 3], bnB[c8 + 3]), 0.0f);
        g1.x = fmaxf(fmaf(f1.x, bnA[c8 + 4], bnB[c8 + 4]), 0.0f);
        g1.y = fmaxf(fmaf(f1.y, bnA[c8 + 5], bnB[c8 + 5]), 0.0f);
        g1.z = fmaxf(fmaf(f1.z, bnA[c8 + 6], bnB[c8 + 6]), 0.0f);
        g1.w = fmaxf(fmaf(f1.w, bnA[c8 + 7], bnB[c8 + 7]), 0.0f);
        *(bf16x8*)(&XS[row][c8]) = cvt8(g0, g1);
    }
    __syncthreads();

    f32x4 acc[2];
    acc[0] = 0.0f; acc[1] = 0.0f;

    for (int k0 = 0; k0 < 128; k0 += 32) {
        bf16x8 a = *(const bf16x8*)(&XS[l15][k0 + 8 * kg]);
        bf16x8 b[2];
#pragma unroll
        for (int ni = 0; ni < 2; ++ni)
            b[ni] = *(const bf16x8*)(M2C + (size_t)((k0 >> 3) + kg) * 2048
                                          + (size_t)(jw + 16 * ni + l15) * 8);
#pragma unroll
        for (int ni = 0; ni < 2; ++ni)
            acc[ni] = __builtin_amdgcn_mfma_f32_16x16x32_bf16(a, b[ni], acc[ni], 0, 0, 0);
    }

#pragma unroll
    for (int ni = 0; ni < 2; ++ni)
#pragma unroll
        for (int r = 0; r < 4; ++r) {
            const size_t idx = (size_t)(i0 + 4 * kg + r) * 256
                             + (jw + 16 * ni + l15);
            out[idx] = oprev[ni][r] + acc[ni][r];
        }
}

// ---------------------------------------------------------------------------
extern "C" void kernel_launch(void* const* d_in, const int* in_sizes, int n_in,
                              void* d_out, int out_size, void* d_ws, size_t ws_size,
                              hipStream_t stream)
{
    const float* x    = (const float*)d_in[0];
    const float* wq   = (const float*)d_in[1];
    const float* bq   = (const float*)d_in[2];
    const float* wk   = (const float*)d_in[3];
    const float* bk   = (const float*)d_in[4];
    const float* wv   = (const float*)d_in[5];
    const float* bv   = (const float*)d_in[6];
    const float* cw   = (const float*)d_in[7];
    const float* cb   = (const float*)d_in[8];
    const float* m1w  = (const float*)d_in[9];
    const float* m2w  = (const float*)d_in[10];
    const float* bng  = (const float*)d_in[11];
    const float* bnb  = (const float*)d_in[12];
    const float* ln1g = (const float*)d_in[13];
    const float* ln1b = (const float*)d_in[14];
    const float* ln2g = (const float*)d_in[15];
    const float* ln2b = (const float*)d_in[16];

    float* outF = (float*)d_out;
    char*  wsb  = (char*)d_ws;
    if (ws_size < WS_NEED) return;

    ushort_t* QbG = (ushort_t*)(wsb + OFF_QB);
    ushort_t* KTC = (ushort_t*)(wsb + OFF_KT);
    ushort_t* VTC = (ushort_t*)(wsb + OFF_VT);
    float*    GP  = (float*)(wsb + OFF_GP);
    ushort_t* MTc = (ushort_t*)(wsb + OFF_MT);
    float*    SVP = (float*)(wsb + OFF_SVP);
    float*    SVC = (float*)(wsb + OFF_SVC);
    float*    RED = (float*)(wsb + OFF_RED);
    float*    ZSP = (float*)(wsb + OFF_ZSP);
    float*    BNS = (float*)(wsb + OFF_BNS);
    ushort_t* WC  = (ushort_t*)(wsb + OFF_WC);
    ushort_t* M1C = (ushort_t*)(wsb + OFF_M1C);
    ushort_t* M2C = (ushort_t*)(wsb + OFF_M2C);
    ushort_t* XB  = (ushort_t*)(wsb + OFF_XB);
    float*    Z   = (float*)(wsb + OFF_GP);   // GP dead after combine_m

    const dim3 b256(256);
    const dim3 b512(512);

    prep_w<<<1169, b256, 0, stream>>>(wq, wk, wv, m1w, m2w, x,
                                      WC, M1C, M2C, XB, QbG, VTC);
    qkv_mfma<<<dim3(256, 3), b256, 0, stream>>>(XB, WC, bq, bk, bv,
                                                QbG, KTC, VTC, RED, SVP);
    g_mfma<<<dim3(4, 8, 16), b256, 0, stream>>>(KTC, VTC, GP);
    combine_m<<<256, b256, 0, stream>>>(GP, cw, RED, SVP, cb, MTc, SVC);
    attn_ln_z_mfma<<<512, b512, 0, stream>>>(QbG, MTc, SVC, x,
                                             ln1g, ln1b, ln2g, ln2b, M1C,
                                             outF, Z, ZSP);
    bn_reduce<<<8, b256, 0, stream>>>(ZSP, BNS);
    gemm_out_mfma<<<512, b512, 0, stream>>>(Z, M2C, BNS, bng, bnb, outF);
}